// Round 10
// baseline (2404.918 us; speedup 1.0000x reference)
//
#include <hip/hip_runtime.h>
#include <hip/hip_bf16.h>

#define T_TOK 8192
#define D_MODEL 1024
#define N_HEADS 16
#define N_KV 4
#define HEAD_D 64
#define SEQ 1024
#define BATCH 8
#define N_EXP 8
#define H_FF 4096
#define KV_D 256

typedef __attribute__((ext_vector_type(8))) short bf16x8;
typedef __attribute__((ext_vector_type(4))) float f32x4;
typedef __attribute__((ext_vector_type(4))) short s16x4;

__device__ __forceinline__ float bf2f(short s) {
    union { unsigned u; float f; } v; v.u = ((unsigned)(unsigned short)s) << 16; return v.f;
}
__device__ __forceinline__ short f2bf(float f) {
    union { float fl; unsigned u; } v; v.fl = f;
    unsigned r = v.u + 0x7FFFu + ((v.u >> 16) & 1u);
    return (short)(r >> 16);
}
// 3-way bf16 split: x ~= hi + mid + lo to ~2^-26 relative
__device__ __forceinline__ void split3(float x, short& a, short& b, short& c) {
    a = f2bf(x);
    float r1 = x - bf2f(a);
    b = f2bf(r1);
    float r2 = r1 - bf2f(b);
    c = f2bf(r2);
}

#define MFMA16x16x32(a,b,c) __builtin_amdgcn_mfma_f32_16x16x32_bf16(a,b,c,0,0,0)

#define GLOAD_LDS16(gp, lp) \
  __builtin_amdgcn_global_load_lds((const __attribute__((address_space(1))) unsigned int*)(const void*)(gp), \
                                   (__attribute__((address_space(3))) unsigned int*)(void*)(lp), 16, 0, 0)

// ---------------- LayerNorm: MODE 0 -> 3 bf16 planes; MODE 1 -> bf16 hi + f32 ----------------
template<int MODE>
__global__ __launch_bounds__(256) void ln_kernel(const float* __restrict__ x,
        const float* __restrict__ g, const float* __restrict__ b,
        short* __restrict__ o0, short* __restrict__ o1, short* __restrict__ o2,
        float* __restrict__ of)
{
    int row = blockIdx.x;
    int tid = threadIdx.x;
    const float4* xr = (const float4*)(x + (size_t)row * D_MODEL);
    float4 v = xr[tid];
    float s = v.x + v.y + v.z + v.w;
    float sq = v.x*v.x + v.y*v.y + v.z*v.z + v.w*v.w;
    #pragma unroll
    for (int o = 32; o > 0; o >>= 1) { s += __shfl_xor(s, o); sq += __shfl_xor(sq, o); }
    __shared__ float red[8];
    int wid = tid >> 6, lane = tid & 63;
    if (lane == 0) { red[wid] = s; red[4 + wid] = sq; }
    __syncthreads();
    s = red[0] + red[1] + red[2] + red[3];
    sq = red[4] + red[5] + red[6] + red[7];
    float mean = s * (1.0f / D_MODEL);
    float var = sq * (1.0f / D_MODEL) - mean * mean;
    float rstd = rsqrtf(var + 1e-5f);
    float4 gg = ((const float4*)g)[tid], bb = ((const float4*)b)[tid];
    float y[4];
    y[0] = (v.x - mean) * rstd * gg.x + bb.x;
    y[1] = (v.y - mean) * rstd * gg.y + bb.y;
    y[2] = (v.z - mean) * rstd * gg.z + bb.z;
    y[3] = (v.w - mean) * rstd * gg.w + bb.w;
    size_t o_off = (size_t)row * D_MODEL + tid * 4;
    if (MODE == 0) {
        s16x4 t0, t1, t2;
        #pragma unroll
        for (int i = 0; i < 4; i++) { short a, b_, c; split3(y[i], a, b_, c); t0[i]=a; t1[i]=b_; t2[i]=c; }
        *(s16x4*)(o0 + o_off) = t0;
        *(s16x4*)(o1 + o_off) = t1;
        *(s16x4*)(o2 + o_off) = t2;
    } else {
        s16x4 t0;
        #pragma unroll
        for (int i = 0; i < 4; i++) t0[i] = f2bf(y[i]);
        *(s16x4*)(o0 + o_off) = t0;
        float4 yo; yo.x = y[0]; yo.y = y[1]; yo.z = y[2]; yo.w = y[3];
        ((float4*)(of + (size_t)row * D_MODEL))[tid] = yo;
    }
}

// ---------------- transpose f32 [R][C] -> bf16 [C][R] (single plane, for MoE weights) ---------
__global__ void transpose_f2b(const float* __restrict__ in, short* __restrict__ out,
                              int R, int C, long in_z, long out_z)
{
    in += (long)blockIdx.z * in_z;
    out += (long)blockIdx.z * out_z;
    __shared__ float tile[32][33];
    int c0 = blockIdx.x * 32, r0 = blockIdx.y * 32;
    int tx = threadIdx.x, ty = threadIdx.y;
    #pragma unroll
    for (int i = 0; i < 32; i += 8)
        tile[ty + i][tx] = in[(long)(r0 + ty + i) * C + c0 + tx];
    __syncthreads();
    #pragma unroll
    for (int i = 0; i < 32; i += 8)
        out[(long)(c0 + ty + i) * R + r0 + tx] = f2bf(tile[tx][ty + i]);
}

// ---------------- transpose f32 [R][C] -> 3 bf16 planes [C][R], plane stride pstride ----------
__global__ void transpose_f2b3(const float* __restrict__ in, short* __restrict__ o0,
                               long pstride, int R, int C)
{
    __shared__ float tile[32][33];
    int c0 = blockIdx.x * 32, r0 = blockIdx.y * 32;
    int tx = threadIdx.x, ty = threadIdx.y;
    #pragma unroll
    for (int i = 0; i < 32; i += 8)
        tile[ty + i][tx] = in[(long)(r0 + ty + i) * C + c0 + tx];
    __syncthreads();
    #pragma unroll
    for (int i = 0; i < 32; i += 8) {
        long oi = (long)(c0 + ty + i) * R + r0 + tx;
        short a, b_, c;
        split3(tile[tx][ty + i], a, b_, c);
        o0[oi] = a; o0[oi + pstride] = b_; o0[oi + 2 * pstride] = c;
    }
}

// ---------------- V transpose + PV key-permutation bake: vb[b][s][256] -> vt[b][kvh][d][key'] -
__global__ void vperm_kernel(const short* __restrict__ in, short* __restrict__ out,
                             long in_pstride, long out_pstride)
{
    int p = blockIdx.z >> 3;
    int b = blockIdx.z & 7;
    in  += p * in_pstride  + (long)b * SEQ * KV_D;
    out += p * out_pstride + (long)b * N_KV * HEAD_D * SEQ;
    __shared__ short tile[32][33];
    int s0 = blockIdx.x * 32, c0 = blockIdx.y * 32;
    int tx = threadIdx.x, ty = threadIdx.y;
    #pragma unroll
    for (int i = 0; i < 32; i += 8)
        tile[ty + i][tx] = in[(long)(s0 + ty + i) * KV_D + c0 + tx];
    __syncthreads();
    // storage position p holds key pi(p): p=g*8+j -> j<4: g*4+j ; j>=4: 16+g*4+(j-4)
    int pc = tx;
    int srckey = (pc & 4) ? (16 + (pc >> 3) * 4 + (pc & 3))
                          : ((pc >> 3) * 4 + (pc & 3));
    #pragma unroll
    for (int i = 0; i < 32; i += 8) {
        int dcol = c0 + ty + i;
        int kvh = dcol >> 6, d = dcol & 63;
        out[((long)kvh * HEAD_D + d) * SEQ + s0 + pc] = tile[srckey][ty + i];
    }
}

// ---------------- split-precision GEMM: C = (A0+A1+A2)(B0+B1+B2)^T + bias ---------------------
// OMODE 0: f32 out (+res). OMODE 2: fused QKV column routing -> q planes / k planes / vb planes.
template<int OMODE, bool RES>
__global__ __launch_bounds__(256) void gemm_split(
    const short* __restrict__ A0, const short* __restrict__ A1, const short* __restrict__ A2,
    const short* __restrict__ B0, const short* __restrict__ B1, const short* __restrict__ B2,
    const float* __restrict__ bias,
    short* __restrict__ O0, short* __restrict__ O1, short* __restrict__ O2,
    short* __restrict__ K0, short* __restrict__ K1, short* __restrict__ K2,
    short* __restrict__ V0, short* __restrict__ V1, short* __restrict__ V2,
    float* __restrict__ Of, const float* __restrict__ res,
    int M, int N, int K)
{
    __shared__ short As[3][128 * 32];
    __shared__ short Bs[3][128 * 32];
    int tid = threadIdx.x;
    int lane = tid & 63, wid = tid >> 6;
    int wr = (wid >> 1) * 64, wc = (wid & 1) * 64;
    int m0 = blockIdx.x * 128, n0 = blockIdx.y * 128;

    long aoff[2]; long boff[2];
    #pragma unroll
    for (int c = 0; c < 2; c++) {
        int ch = c * 256 + tid;
        int row = ch >> 2, seg = (ch & 3) * 8;
        aoff[c] = (long)(m0 + row) * K + seg;
        boff[c] = (long)(n0 + row) * K + seg;
    }
    f32x4 acc[4][4];
    #pragma unroll
    for (int i = 0; i < 4; i++)
      #pragma unroll
      for (int j = 0; j < 4; j++) acc[i][j] = (f32x4){0.f, 0.f, 0.f, 0.f};

    int r = lane & 15, g = lane >> 4;
    const int kiters = K >> 5;
    const short* Ap[3] = {A0, A1, A2};
    const short* Bp[3] = {B0, B1, B2};
    for (int kt = 0; kt < kiters; kt++) {
        int k0 = kt << 5;
        #pragma unroll
        for (int p = 0; p < 3; p++) {
            #pragma unroll
            for (int c = 0; c < 2; c++) {
                GLOAD_LDS16(Ap[p] + aoff[c] + k0, &As[p][(c * 256 + tid) * 8]);
                GLOAD_LDS16(Bp[p] + boff[c] + k0, &Bs[p][(c * 256 + tid) * 8]);
            }
        }
        __syncthreads();
        bf16x8 af[3][4], bfr[3][4];
        #pragma unroll
        for (int p = 0; p < 3; p++)
          #pragma unroll
          for (int i = 0; i < 4; i++) {
            af[p][i]  = *(const bf16x8*)(&As[p][(wr + i * 16 + r) * 32 + g * 8]);
            bfr[p][i] = *(const bf16x8*)(&Bs[p][(wc + i * 16 + r) * 32 + g * 8]);
          }
        #pragma unroll
        for (int i = 0; i < 4; i++)
          #pragma unroll
          for (int j = 0; j < 4; j++) {
            f32x4 a = acc[i][j];
            a = MFMA16x16x32(af[0][i], bfr[0][j], a);
            a = MFMA16x16x32(af[0][i], bfr[1][j], a);
            a = MFMA16x16x32(af[1][i], bfr[0][j], a);
            a = MFMA16x16x32(af[0][i], bfr[2][j], a);
            a = MFMA16x16x32(af[1][i], bfr[1][j], a);
            a = MFMA16x16x32(af[2][i], bfr[0][j], a);
            acc[i][j] = a;
          }
        __syncthreads();
    }
    #pragma unroll
    for (int i = 0; i < 4; i++) {
      #pragma unroll
      for (int j = 0; j < 4; j++) {
        #pragma unroll
        for (int qq = 0; qq < 4; qq++) {
            long row = m0 + wr + i * 16 + g * 4 + qq;
            int col = n0 + wc + j * 16 + r;
            float v = acc[i][j][qq] + bias[col];
            if (OMODE == 0) {
                long oi = row * N + col;
                if (RES) v += res[oi];
                Of[oi] = v;
            } else {
                short a, b_, c;
                split3(v, a, b_, c);
                if (col < 1024) {
                    long oi = row * 1024 + col;
                    O0[oi] = a; O1[oi] = b_; O2[oi] = c;
                } else if (col < 1280) {
                    long oi = row * 256 + (col - 1024);
                    K0[oi] = a; K1[oi] = b_; K2[oi] = c;
                } else {
                    long oi = row * 256 + (col - 1280);
                    V0[oi] = a; V1[oi] = b_; V2[oi] = c;
                }
            }
        }
      }
    }
}

// ---------------- MoE GEMM: 256x256 tile, BK=64, 8 waves, 2-phase dbuf, T2 XOR swizzle --------
// LDS reads: chunk(8 bf16) index XOR'd with row&7 (read side) matched by inverse-swizzled
// global source (stage side) -> 8 accesses/bank minimum (was 16-way collision in round 8).
// Sync: __syncthreads() 2-phase (round-7-proven race-free; stage(t+1) hidden under ~2300cy
// of compute+LDS reads). LDS 128KB -> 1 block/CU; acc[8][4]=128 AGPR.
template<bool GELU, bool OUTF32>
__global__ __launch_bounds__(512) void gemm_moe256(
    const short* __restrict__ A, const short* __restrict__ Bt,
    const float* __restrict__ bias, void* __restrict__ Cout,
    int N, int K,
    const int* __restrict__ counts, const int* __restrict__ bases,
    long bt_estride, int bias_estride)
{
    int e = blockIdx.z;
    int cnt = counts[e];
    if ((int)blockIdx.x * 256 >= cnt) return;
    int rowbase = bases[e];
    Bt += (long)e * bt_estride;
    bias += (long)e * bias_estride;

    __shared__ short As[2][256 * 64];   // 2 x 32KB
    __shared__ short Bs[2][256 * 64];   // 2 x 32KB  (128KB total)
    int tid = threadIdx.x;
    int lane = tid & 63, wid = tid >> 6;
    int wr = (wid >> 2) * 128, wc = (wid & 3) * 64;   // 2x4 wave grid
    int m0 = blockIdx.x * 256, n0 = blockIdx.y * 256;

    // staging: 4 chunks (16B) per thread per operand; ch = c*512+tid -> row=ch>>3, phys chunk=ch&7
    // global source column = (physchunk ^ (row&7)) * 8   (inverse-swizzle; involution)
    long aoff[4]; long boff[4];
    #pragma unroll
    for (int c = 0; c < 4; c++) {
        int ch = c * 512 + tid;
        int row = ch >> 3;
        int seg = ((ch & 7) ^ (row & 7)) * 8;
        int grow = m0 + row;
        long arow = rowbase + (grow < cnt ? grow : 0);
        aoff[c] = arow * (long)K + seg;
        boff[c] = (long)(n0 + row) * K + seg;
    }
    f32x4 acc[8][4];
    #pragma unroll
    for (int i = 0; i < 8; i++)
      #pragma unroll
      for (int j = 0; j < 4; j++) acc[i][j] = (f32x4){0.f, 0.f, 0.f, 0.f};

    int r = lane & 15, g = lane >> 4;
    const int kiters = K >> 6;

    auto stage = [&](int buf, int k0) {   // 8 global_load_lds (4 A + 4 B)
        #pragma unroll
        for (int c = 0; c < 4; c++) {
            GLOAD_LDS16(A + aoff[c] + k0, &As[buf][(c * 512 + tid) * 8]);
            GLOAD_LDS16(Bt + boff[c] + k0, &Bs[buf][(c * 512 + tid) * 8]);
        }
    };

    stage(0, 0);
    __syncthreads();

    for (int kt = 0; kt < kiters; kt++) {
        int cur = kt & 1;
        if (kt + 1 < kiters) stage(cur ^ 1, (kt + 1) << 6);
        #pragma unroll
        for (int kh = 0; kh < 2; kh++) {   // two K=32 slices of the 64-wide tile
            bf16x8 af[8], bfr[4];
            #pragma unroll
            for (int i = 0; i < 8; i++) {
                int row = wr + i * 16 + r;
                int chunk = (kh * 4 + g) ^ (row & 7);
                af[i] = *(const bf16x8*)(&As[cur][row * 64 + chunk * 8]);
            }
            #pragma unroll
            for (int j = 0; j < 4; j++) {
                int row = wc + j * 16 + r;
                int chunk = (kh * 4 + g) ^ (row & 7);
                bfr[j] = *(const bf16x8*)(&Bs[cur][row * 64 + chunk * 8]);
            }
            #pragma unroll
            for (int i = 0; i < 8; i++)
              #pragma unroll
              for (int j = 0; j < 4; j++)
                acc[i][j] = MFMA16x16x32(af[i], bfr[j], acc[i][j]);
        }
        __syncthreads();   // drains this iter's stage (had full compute phase to fly)
    }
    #pragma unroll
    for (int i = 0; i < 8; i++) {
      #pragma unroll
      for (int j = 0; j < 4; j++) {
        #pragma unroll
        for (int qq = 0; qq < 4; qq++) {
            int row = m0 + wr + i * 16 + g * 4 + qq;
            if (row >= cnt) continue;
            int col = n0 + wc + j * 16 + r;
            float v = acc[i][j][qq] + bias[col];
            if (GELU) v = 0.5f * v * (1.0f + erff(v * 0.70710678118f));
            long orow = (long)(rowbase + row);
            if (OUTF32) ((float*)Cout)[orow * N + col] = v;
            else        ((short*)Cout)[orow * N + col] = f2bf(v);
        }
      }
    }
}

// ---------------- token gather: xg[pos] = src[gidx[pos]] (coalesced 16B lanes) ----------------
__global__ __launch_bounds__(256) void gather_kernel(const short* __restrict__ src,
    const int* __restrict__ gidx, short* __restrict__ dst)
{
    long idx = (long)blockIdx.x * 256 + threadIdx.x;
    int row = (int)(idx >> 7);
    int c = (int)(idx & 127);
    int t = gidx[row];
    *(bf16x8*)(dst + (size_t)row * D_MODEL + c * 8) =
        *(const bf16x8*)(src + (size_t)t * D_MODEL + c * 8);
}

// ---------------- split-precision flash attention: LDS-staged K/V, register P -----------------
__global__ __launch_bounds__(256) void attn_split(
    const short* __restrict__ q0p, const short* __restrict__ q1p, const short* __restrict__ q2p,
    const short* __restrict__ k0p, const short* __restrict__ k1p, const short* __restrict__ k2p,
    const short* __restrict__ v0p, const short* __restrict__ v1p, const short* __restrict__ v2p,
    short* __restrict__ ao0, short* __restrict__ ao1, short* __restrict__ ao2)
{
    __shared__ short lds[2][2][3][2048];   // [buf][K/V][plane][4KB]
    int tid = threadIdx.x;
    int wid = tid >> 6, lane = tid & 63;
    int r = lane & 15, g = lane >> 4;
    int bh = blockIdx.y;
    int b = bh >> 4, h = bh & 15, kvh = h >> 2;
    int q0_ = blockIdx.x * 64 + wid * 16;

    size_t qoff = ((size_t)(b * SEQ + q0_ + r)) * D_MODEL + h * HEAD_D + g * 8;
    bf16x8 qf[3][2];
    qf[0][0] = *(const bf16x8*)(q0p + qoff); qf[0][1] = *(const bf16x8*)(q0p + qoff + 32);
    qf[1][0] = *(const bf16x8*)(q1p + qoff); qf[1][1] = *(const bf16x8*)(q1p + qoff + 32);
    qf[2][0] = *(const bf16x8*)(q2p + qoff); qf[2][1] = *(const bf16x8*)(q2p + qoff + 32);

    size_t kbo = (size_t)(b * SEQ) * KV_D + kvh * HEAD_D;
    const short* kb[3] = {k0p + kbo, k1p + kbo, k2p + kbo};
    size_t vbo = (size_t)((b * N_KV + kvh) * HEAD_D) * SEQ;
    const short* vtp[3] = {v0p + vbo, v1p + vbo, v2p + vbo};

    int krow = tid >> 3;
    int ksrc = ((tid & 7) * 16) ^ ((krow & 7) << 4);
    int vrow = tid >> 2;
    int vsrc = ((tid & 3) * 16) ^ (((vrow >> 1) & 3) << 4);

    auto stage = [&](int buf, int kt) {
        int key0 = kt * 32;
        #pragma unroll
        for (int p = 0; p < 3; p++) {
            const short* src = kb[p] + (size_t)(key0 + krow) * KV_D + (ksrc >> 1);
            GLOAD_LDS16(src, &lds[buf][0][p][tid * 8]);
        }
        #pragma unroll
        for (int p = 0; p < 3; p++) {
            const short* src = vtp[p] + (size_t)vrow * SEQ + key0 + (vsrc >> 1);
            GLOAD_LDS16(src, &lds[buf][1][p][tid * 8]);
        }
    };

    float m_run = -1e30f, lsum = 0.f;
    f32x4 o[4];
    #pragma unroll
    for (int i = 0; i < 4; i++) o[i] = (f32x4){0.f, 0.f, 0.f, 0.f};

    stage(0, 0);
    __syncthreads();

    for (int kt = 0; kt < SEQ / 32; kt++) {
        int cur = kt & 1;
        if (kt < SEQ / 32 - 1) stage(cur ^ 1, kt + 1);

        f32x4 sT0, sT1;
        #pragma unroll
        for (int kh = 0; kh < 2; kh++) {
            f32x4 s = (f32x4){0.f, 0.f, 0.f, 0.f};
            #pragma unroll
            for (int c = 0; c < 2; c++) {
                int koff = ((kh * 16 + r) * 128 + ((c * 64 + g * 16) ^ ((r & 7) << 4))) >> 1;
                bf16x8 k0f = *(const bf16x8*)(&lds[cur][0][0][koff]);
                bf16x8 k1f = *(const bf16x8*)(&lds[cur][0][1][koff]);
                bf16x8 k2f = *(const bf16x8*)(&lds[cur][0][2][koff]);
                s = MFMA16x16x32(k0f, qf[0][c], s);
                s = MFMA16x16x32(k1f, qf[0][c], s);
                s = MFMA16x16x32(k0f, qf[1][c], s);
                s = MFMA16x16x32(k2f, qf[0][c], s);
                s = MFMA16x16x32(k1f, qf[1][c], s);
                s = MFMA16x16x32(k0f, qf[2][c], s);
            }
            if (kh == 0) sT0 = s; else sT1 = s;
        }

        float a0[4], a1[4];
        float vmx = -1e30f;
        #pragma unroll
        for (int rr = 0; rr < 4; rr++) {
            a0[rr] = sT0[rr] * 0.125f;
            a1[rr] = sT1[rr] * 0.125f;
            vmx = fmaxf(vmx, fmaxf(a0[rr], a1[rr]));
        }
        vmx = fmaxf(vmx, __shfl_xor(vmx, 16));
        vmx = fmaxf(vmx, __shfl_xor(vmx, 32));
        float mn = fmaxf(m_run, vmx);
        float alpha = __expf(m_run - mn);
        m_run = mn;
        float p0[4], p1[4], ps = 0.f;
        #pragma unroll
        for (int rr = 0; rr < 4; rr++) {
            p0[rr] = __expf(a0[rr] - mn);
            p1[rr] = __expf(a1[rr] - mn);
            ps += p0[rr] + p1[rr];
        }
        ps += __shfl_xor(ps, 16);
        ps += __shfl_xor(ps, 32);
        lsum = lsum * alpha + ps;
        bf16x8 pw0, pw1, pw2;
        #pragma unroll
        for (int rr = 0; rr < 4; rr++) {
            short h0_, m0_, l0_, h1_, m1_, l1_;
            split3(p0[rr], h0_, m0_, l0_);
            split3(p1[rr], h1_, m1_, l1_);
            pw0[rr] = h0_; pw0[4 + rr] = h1_;
            pw1[rr] = m0_; pw1[4 + rr] = m1_;
            pw2[rr] = l0_; pw2[4 + rr] = l1_;
        }
        float af[4];
        #pragma unroll
        for (int rr = 0; rr < 4; rr++) af[rr] = __shfl(alpha, g * 4 + rr);
        #pragma unroll
        for (int fc = 0; fc < 4; fc++)
          #pragma unroll
          for (int rr = 0; rr < 4; rr++) o[fc][rr] *= af[rr];

        #pragma unroll
        for (int fc = 0; fc < 4; fc++) {
            int voff = ((fc * 16 + r) * 64 + ((g * 16) ^ (((r >> 1) & 3) << 4))) >> 1;
            bf16x8 bv0 = *(const bf16x8*)(&lds[cur][1][0][voff]);
            bf16x8 bv1 = *(const bf16x8*)(&lds[cur][1][1][voff]);
            bf16x8 bv2 = *(const bf16x8*)(&lds[cur][1][2][voff]);
            f32x4 a = o[fc];
            a = MFMA16x16x32(pw0, bv0, a);
            a = MFMA16x16x32(pw0, bv1, a);
            a = MFMA16x16x32(pw1, bv0, a);
            a = MFMA16x16x32(pw0, bv2, a);
            a = MFMA16x16x32(pw1, bv1, a);
            a = MFMA16x16x32(pw2, bv0, a);
            o[fc] = a;
        }

        __syncthreads();
    }

    float linv[4];
    #pragma unroll
    for (int rr = 0; rr < 4; rr++) linv[rr] = 1.0f / __shfl(lsum, g * 4 + rr);
    #pragma unroll
    for (int fc = 0; fc < 4; fc++) {
        #pragma unroll
        for (int rr = 0; rr < 4; rr++) {
            float v = o[fc][rr] * linv[rr];
            int qrow = q0_ + g * 4 + rr;
            int col = h * HEAD_D + fc * 16 + r;
            size_t oi = ((size_t)(b * SEQ + qrow)) * D_MODEL + col;
            short a_, b_, c_;
            split3(v, a_, b_, c_);
            ao0[oi] = a_; ao1[oi] = b_; ao2[oi] = c_;
        }
    }
}

// ---------------- router (f32 exact, no atomics) ----------------------------------------------
__global__ __launch_bounds__(256) void router_kernel(
    const float* __restrict__ h2f, const float* __restrict__ Wr, const float* __restrict__ br,
    int* __restrict__ topi, float* __restrict__ topw)
{
    int wid = threadIdx.x >> 6, lane = threadIdx.x & 63;
    int t = blockIdx.x * 4 + wid;
    const float4* hr = (const float4*)(h2f + (size_t)t * D_MODEL + lane * 16);
    float acc[8] = {0.f,0.f,0.f,0.f,0.f,0.f,0.f,0.f};
    #pragma unroll
    for (int ii = 0; ii < 4; ii++) {
        float4 hv4 = hr[ii];
        float hv[4] = {hv4.x, hv4.y, hv4.z, hv4.w};
        #pragma unroll
        for (int c = 0; c < 4; c++) {
            int idx = lane * 16 + ii * 4 + c;
            const float4* w4 = (const float4*)(Wr + (size_t)idx * 8);
            float4 w0 = w4[0], w1 = w4[1];
            acc[0] += hv[c] * w0.x; acc[1] += hv[c] * w0.y;
            acc[2] += hv[c] * w0.z; acc[3] += hv[c] * w0.w;
            acc[4] += hv[c] * w1.x; acc[5] += hv[c] * w1.y;
            acc[6] += hv[c] * w1.z; acc[7] += hv[c] * w1.w;
        }
    }
    #pragma unroll
    for (int e = 0; e < 8; e++) {
        float v = acc[e];
        #pragma unroll
        for (int o = 32; o > 0; o >>= 1) v += __shfl_xor(v, o);
        acc[e] = v + br[e];
    }
    if (lane == 0) {
        int i0 = 0; float l0 = acc[0];
        #pragma unroll
        for (int e = 1; e < 8; e++) if (acc[e] > l0) { l0 = acc[e]; i0 = e; }
        int i1 = -1; float l1 = -1e30f;
        #pragma unroll
        for (int e = 0; e < 8; e++) if (e != i0 && acc[e] > l1) { l1 = acc[e]; i1 = e; }
        float e1 = expf(l1 - l0);
        float w0 = 1.0f / (1.0f + e1);
        topi[t * 2] = i0; topi[t * 2 + 1] = i1;
        topw[t * 2] = w0; topw[t * 2 + 1] = e1 * w0;
    }
}

// ---------------- histogram + prefix (1 block) ------------------------------------------------
__global__ __launch_bounds__(1024) void hist_kernel(const int* __restrict__ topi,
    int* __restrict__ counts, int* __restrict__ bases, int* __restrict__ cursor)
{
    __shared__ int hc[8];
    int tid = threadIdx.x;
    if (tid < 8) hc[tid] = 0;
    __syncthreads();
    int c[8] = {0,0,0,0,0,0,0,0};
    for (int i = tid; i < 2 * T_TOK; i += 1024) {
        int e = topi[i];
        #pragma unroll
        for (int q = 0; q < 8; q++) c[q] += (e == q) ? 1 : 0;
    }
    #pragma unroll
    for (int e = 0; e < 8; e++) {
        int v = c[e];
        #pragma unroll
        for (int o = 32; o > 0; o >>= 1) v += __shfl_xor(v, o);
        if ((tid & 63) == 0) atomicAdd(&hc[e], v);
    }
    __syncthreads();
    if (tid == 0) {
        int s = 0;
        #pragma unroll
        for (int e = 0; e < 8; e++) { bases[e] = s; counts[e] = hc[e]; s += hc[e]; }
    }
    if (tid >= 64 && tid < 72) cursor[tid - 64] = 0;
}

// ---------------- assign with wave-aggregated atomics -----------------------------------------
__global__ __launch_bounds__(256) void assign_kernel(const int* __restrict__ topi,
    const int* __restrict__ bases, int* __restrict__ cursor,
    int* __restrict__ gidx, int* __restrict__ pos_of)
{
    int t = blockIdx.x * 256 + threadIdx.x;
    int lane = threadIdx.x & 63;
    #pragma unroll
    for (int kk = 0; kk < 2; kk++) {
        int e = topi[t * 2 + kk];
        #pragma unroll
        for (int e8 = 0; e8 < 8; e8++) {
            bool mine = (e == e8);
            unsigned long long m = __ballot(mine);
            if (m == 0ull) continue;
            int lead = __ffsll((long long)m) - 1;
            int base = 0;
            if (lane == lead) base = atomicAdd(&cursor[e8], __popcll(m));
            base = __shfl(base, lead);
            if (mine) {
                int pos = bases[e8] + base + (int)__popcll(m & ((1ull << lane) - 1ull));
                gidx[pos] = t;
                pos_of[t * 2 + kk] = pos;
            }
        }
    }
}

__global__ void biascat_kernel(const float* __restrict__ bq, const float* __restrict__ bk,
                               const float* __restrict__ bv, float* __restrict__ out)
{
    int i = blockIdx.x * 256 + threadIdx.x;
    if (i < 1024) out[i] = bq[i];
    else if (i < 1280) out[i] = bk[i - 1024];
    else if (i < 1536) out[i] = bv[i - 1280];
}

__global__ __launch_bounds__(256) void combine_kernel(const float* __restrict__ x2,
    const float* __restrict__ y, const int* __restrict__ pos_of,
    const float* __restrict__ topw, float* __restrict__ out)
{
    long idx = (long)blockIdx.x * 256 + threadIdx.x;
    int t = (int)(idx >> 8);
    int c = (int)(idx & 255);
    int p0 = pos_of[t * 2], p1 = pos_of[t * 2 + 1];
    float w0 = topw[t * 2], w1 = topw[t * 2 + 1];
    float4 a = ((const float4*)(x2 + (size_t)t * D_MODEL))[c];
    float4 u = ((const float4*)(y + (size_t)p0 * D_MODEL))[c];
    float4 v = ((const float4*)(y + (size_t)p1 * D_MODEL))[c];
    float4 o;
    o.x = a.x + w0 * u.x + w1 * v.x;
    o.y = a.y + w0 * u.y + w1 * v.y;
    o.z = a.z + w0 * u.z + w1 * v.z;
    o.w = a.w + w0 * u.w + w1 * v.w;
    ((float4*)(out + (size_t)t * D_MODEL))[c] = o;
}

extern "C" void kernel_launch(void* const* d_in, const int* in_sizes, int n_in,
                              void* d_out, int out_size, void* d_ws, size_t ws_size,
                              hipStream_t stream)
{
    (void)in_sizes; (void)n_in; (void)out_size; (void)ws_size;
    const float* x   = (const float*)d_in[0];
    const float* Wq  = (const float*)d_in[1];
    const float* bq  = (const float*)d_in[2];
    const float* Wk  = (const float*)d_in[3];
    const float* bk  = (const float*)d_in[4];
    const float* Wv  = (const float*)d_in[5];
    const float* bv  = (const float*)d_in[6];
    const float* Wo  = (const float*)d_in[7];
    const float* bo  = (const float*)d_in[8];
    const float* g1  = (const float*)d_in[9];
    const float* b1n = (const float*)d_in[10];
    const float* g2  = (const float*)d_in[11];
    const float* b2n = (const float*)d_in[12];
    const float* Wr  = (const float*)d_in[13];
    const float* br  = (const float*)d_in[14];
    const float* W1  = (const float*)d_in[15];
    const float* b1e = (const float*)d_in[16];
    const float* W2  = (const float*)d_in[17];
    const float* b2e = (const float*)d_in[18];
    float* out = (float*)d_out;

    size_t off = 0;
    auto alloc = [&](size_t n) {
        size_t cur = off;
        off = (cur + n + 255) & ~(size_t)255;
        return (void*)((char*)d_ws + cur);
    };
    const size_t PD = (size_t)T_TOK * D_MODEL;
    const size_t PK = (size_t)T_TOK * KV_D;
    const size_t WQKV = (size_t)1536 * 1024;
    const size_t WQP  = (size_t)D_MODEL * D_MODEL;
    short* blkA   = (short*)alloc(3 * PD * 2);       // h planes -> ao planes -> xg (aliased)
    short* blkB   = (short*)alloc(3 * PD * 2);       // q planes -> h2hi + h2f
    short* kpl    = (short*)alloc(3 * PK * 2);
    short* vbpl   = (short*)alloc(3 * PK * 2);
    short* vtpl   = (short*)alloc(3 * PK * 2);
    float* x2     = (float*)alloc(PD * 4);
    short* WqkvT3 = (short*)alloc(3 * WQKV * 2);
    short* WoT3   = (short*)alloc(3 * WQP * 2);
    float* bqkv   = (float*)alloc(1536 * 4);
    short* W1T    = (short*)alloc((size_t)N_EXP * H_FF * D_MODEL * 2);
    short* W2T    = (short*)alloc((size_t)N_EXP * D_MODEL * H_FF * 2);
    short* mid    = (short*)alloc((size_t)(2 * T_TOK) * H_FF * 2);
    float* yb     = (float*)alloc((size_t)(2 * T_TOK) * D_MODEL * 4);
    int* counts = (int*)alloc(256);
    int* bases  = (int*)alloc(256);
    int* cursor = (int*)alloc(256);
    int* topi   = (int*)alloc((size_t)T_TOK * 2 * 4);
    float* topw = (float*)alloc((size_t)T_TOK * 2 * 4);
    int* posof  = (int*)alloc((size_t)T_TOK * 2 * 4);
    int* gidx   = (int*)alloc((size_t)2 * T_TOK * 4);

    short* h0 = blkA, *h1 = blkA + PD, *h2p = blkA + 2 * PD;
    short* ao0 = blkA, *ao1 = blkA + PD, *ao2 = blkA + 2 * PD;
    short* xg = blkA;   // alias: blkA (h/ao planes) is dead after the O-projection;
                        // gather (32 MiB) runs strictly later.
    short* q0 = blkB, *q1 = blkB + PD, *q2 = blkB + 2 * PD;
    short* h2hi = blkB;
    float* h2f = (float*)(blkB + PD);
    short* k0 = kpl, *k1 = kpl + PK, *k2 = kpl + 2 * PK;
    short* vb0 = vbpl, *vb1 = vbpl + PK, *vb2 = vbpl + 2 * PK;
    short* vt0 = vtpl, *vt1 = vtpl + PK, *vt2 = vtpl + 2 * PK;

    dim3 tb(32, 8);
    transpose_f2b3<<<dim3(32, 32), tb, 0, stream>>>(Wq, WqkvT3,                   (long)WQKV, 1024, 1024);
    transpose_f2b3<<<dim3(8, 32),  tb, 0, stream>>>(Wk, WqkvT3 + (size_t)1024 * 1024, (long)WQKV, 1024, 256);
    transpose_f2b3<<<dim3(8, 32),  tb, 0, stream>>>(Wv, WqkvT3 + (size_t)1280 * 1024, (long)WQKV, 1024, 256);
    transpose_f2b3<<<dim3(32, 32), tb, 0, stream>>>(Wo, WoT3, (long)WQP, 1024, 1024);
    transpose_f2b<<<dim3(128, 32, 8), tb, 0, stream>>>(W1, W1T, 1024, 4096,
        (long)1024 * 4096, (long)4096 * 1024);
    transpose_f2b<<<dim3(32, 128, 8), tb, 0, stream>>>(W2, W2T, 4096, 1024,
        (long)4096 * 1024, (long)1024 * 4096);
    biascat_kernel<<<6, 256, 0, stream>>>(bq, bk, bv, bqkv);

    ln_kernel<0><<<T_TOK, 256, 0, stream>>>(x, g1, b1n, h0, h1, h2p, nullptr);

    // fused QKV projection
    gemm_split<2, false><<<dim3(64, 12), 256, 0, stream>>>(
        h0, h1, h2p, WqkvT3, WqkvT3 + WQKV, WqkvT3 + 2 * WQKV, bqkv,
        q0, q1, q2, k0, k1, k2, vb0, vb1, vb2,
        nullptr, nullptr, T_TOK, 1536, 1024);

    vperm_kernel<<<dim3(32, 8, 24), tb, 0, stream>>>(vbpl, vtpl, (long)PK, (long)PK);

    attn_split<<<dim3(16, 128), 256, 0, stream>>>(q0, q1, q2, k0, k1, k2,
        vt0, vt1, vt2, ao0, ao1, ao2);

    gemm_split<0, true><<<dim3(64, 8), 256, 0, stream>>>(
        ao0, ao1, ao2, WoT3, WoT3 + WQP, WoT3 + 2 * WQP, bo,
        nullptr, nullptr, nullptr, nullptr, nullptr, nullptr, nullptr, nullptr, nullptr,
        x2, x, T_TOK, 1024, 1024);

    ln_kernel<1><<<T_TOK, 256, 0, stream>>>(x2, g2, b2n, h2hi, nullptr, nullptr, h2f);

    router_kernel<<<2048, 256, 0, stream>>>(h2f, Wr, br, topi, topw);
    hist_kernel<<<1, 1024, 0, stream>>>(topi, counts, bases, cursor);
    assign_kernel<<<32, 256, 0, stream>>>(topi, bases, cursor, gidx, posof);
    gather_kernel<<<8192, 256, 0, stream>>>(h2hi, gidx, xg);

    gemm_moe256<true, false><<<dim3(32, 16, 8), 512, 0, stream>>>(
        xg, W1T, b1e, mid, 4096, 1024, counts, bases,
        (long)H_FF * D_MODEL, H_FF);
    gemm_moe256<false, true><<<dim3(32, 4, 8), 512, 0, stream>>>(
        mid, W2T, b2e, yb, 1024, 4096, counts, bases,
        (long)D_MODEL * H_FF, D_MODEL);

    combine_kernel<<<8192, 256, 0, stream>>>(x2, yb, posof, topw, out);
}

// Round 11
// 1582.441 us; speedup vs baseline: 1.5198x; 1.5198x over previous
//
#include <hip/hip_runtime.h>
#include <hip/hip_bf16.h>

#define T_TOK 8192
#define D_MODEL 1024
#define N_HEADS 16
#define N_KV 4
#define HEAD_D 64
#define SEQ 1024
#define BATCH 8
#define N_EXP 8
#define H_FF 4096
#define KV_D 256

typedef __attribute__((ext_vector_type(8))) short bf16x8;
typedef __attribute__((ext_vector_type(4))) float f32x4;
typedef __attribute__((ext_vector_type(4))) short s16x4;

__device__ __forceinline__ float bf2f(short s) {
    union { unsigned u; float f; } v; v.u = ((unsigned)(unsigned short)s) << 16; return v.f;
}
__device__ __forceinline__ short f2bf(float f) {
    union { float fl; unsigned u; } v; v.fl = f;
    unsigned r = v.u + 0x7FFFu + ((v.u >> 16) & 1u);
    return (short)(r >> 16);
}
// 3-way bf16 split: x ~= hi + mid + lo to ~2^-26 relative
__device__ __forceinline__ void split3(float x, short& a, short& b, short& c) {
    a = f2bf(x);
    float r1 = x - bf2f(a);
    b = f2bf(r1);
    float r2 = r1 - bf2f(b);
    c = f2bf(r2);
}
// bank-conflict swizzle for BK=32 rows (4 x 16B chunks/row): spreads 64B-stride rows
// across bank quads; involution (applied to stage source AND ds_read chunk index).
__device__ __forceinline__ int swz4(int row) {
    return (row & 3) ^ ((row >> 2) & 3);
}

#define MFMA16x16x32(a,b,c) __builtin_amdgcn_mfma_f32_16x16x32_bf16(a,b,c,0,0,0)

#define GLOAD_LDS16(gp, lp) \
  __builtin_amdgcn_global_load_lds((const __attribute__((address_space(1))) unsigned int*)(const void*)(gp), \
                                   (__attribute__((address_space(3))) unsigned int*)(void*)(lp), 16, 0, 0)

// ---------------- LayerNorm: MODE 0 -> 3 bf16 planes; MODE 1 -> bf16 hi + f32 ----------------
template<int MODE>
__global__ __launch_bounds__(256) void ln_kernel(const float* __restrict__ x,
        const float* __restrict__ g, const float* __restrict__ b,
        short* __restrict__ o0, short* __restrict__ o1, short* __restrict__ o2,
        float* __restrict__ of)
{
    int row = blockIdx.x;
    int tid = threadIdx.x;
    const float4* xr = (const float4*)(x + (size_t)row * D_MODEL);
    float4 v = xr[tid];
    float s = v.x + v.y + v.z + v.w;
    float sq = v.x*v.x + v.y*v.y + v.z*v.z + v.w*v.w;
    #pragma unroll
    for (int o = 32; o > 0; o >>= 1) { s += __shfl_xor(s, o); sq += __shfl_xor(sq, o); }
    __shared__ float red[8];
    int wid = tid >> 6, lane = tid & 63;
    if (lane == 0) { red[wid] = s; red[4 + wid] = sq; }
    __syncthreads();
    s = red[0] + red[1] + red[2] + red[3];
    sq = red[4] + red[5] + red[6] + red[7];
    float mean = s * (1.0f / D_MODEL);
    float var = sq * (1.0f / D_MODEL) - mean * mean;
    float rstd = rsqrtf(var + 1e-5f);
    float4 gg = ((const float4*)g)[tid], bb = ((const float4*)b)[tid];
    float y[4];
    y[0] = (v.x - mean) * rstd * gg.x + bb.x;
    y[1] = (v.y - mean) * rstd * gg.y + bb.y;
    y[2] = (v.z - mean) * rstd * gg.z + bb.z;
    y[3] = (v.w - mean) * rstd * gg.w + bb.w;
    size_t o_off = (size_t)row * D_MODEL + tid * 4;
    if (MODE == 0) {
        s16x4 t0, t1, t2;
        #pragma unroll
        for (int i = 0; i < 4; i++) { short a, b_, c; split3(y[i], a, b_, c); t0[i]=a; t1[i]=b_; t2[i]=c; }
        *(s16x4*)(o0 + o_off) = t0;
        *(s16x4*)(o1 + o_off) = t1;
        *(s16x4*)(o2 + o_off) = t2;
    } else {
        s16x4 t0;
        #pragma unroll
        for (int i = 0; i < 4; i++) t0[i] = f2bf(y[i]);
        *(s16x4*)(o0 + o_off) = t0;
        float4 yo; yo.x = y[0]; yo.y = y[1]; yo.z = y[2]; yo.w = y[3];
        ((float4*)(of + (size_t)row * D_MODEL))[tid] = yo;
    }
}

// ---------------- transpose f32 [R][C] -> bf16 [C][R] (single plane, for MoE weights) ---------
__global__ void transpose_f2b(const float* __restrict__ in, short* __restrict__ out,
                              int R, int C, long in_z, long out_z)
{
    in += (long)blockIdx.z * in_z;
    out += (long)blockIdx.z * out_z;
    __shared__ float tile[32][33];
    int c0 = blockIdx.x * 32, r0 = blockIdx.y * 32;
    int tx = threadIdx.x, ty = threadIdx.y;
    #pragma unroll
    for (int i = 0; i < 32; i += 8)
        tile[ty + i][tx] = in[(long)(r0 + ty + i) * C + c0 + tx];
    __syncthreads();
    #pragma unroll
    for (int i = 0; i < 32; i += 8)
        out[(long)(c0 + ty + i) * R + r0 + tx] = f2bf(tile[tx][ty + i]);
}

// ---------------- transpose f32 [R][C] -> 3 bf16 planes [C][R], plane stride pstride ----------
__global__ void transpose_f2b3(const float* __restrict__ in, short* __restrict__ o0,
                               long pstride, int R, int C)
{
    __shared__ float tile[32][33];
    int c0 = blockIdx.x * 32, r0 = blockIdx.y * 32;
    int tx = threadIdx.x, ty = threadIdx.y;
    #pragma unroll
    for (int i = 0; i < 32; i += 8)
        tile[ty + i][tx] = in[(long)(r0 + ty + i) * C + c0 + tx];
    __syncthreads();
    #pragma unroll
    for (int i = 0; i < 32; i += 8) {
        long oi = (long)(c0 + ty + i) * R + r0 + tx;
        short a, b_, c;
        split3(tile[tx][ty + i], a, b_, c);
        o0[oi] = a; o0[oi + pstride] = b_; o0[oi + 2 * pstride] = c;
    }
}

// ---------------- V transpose + PV key-permutation bake: vb[b][s][256] -> vt[b][kvh][d][key'] -
__global__ void vperm_kernel(const short* __restrict__ in, short* __restrict__ out,
                             long in_pstride, long out_pstride)
{
    int p = blockIdx.z >> 3;
    int b = blockIdx.z & 7;
    in  += p * in_pstride  + (long)b * SEQ * KV_D;
    out += p * out_pstride + (long)b * N_KV * HEAD_D * SEQ;
    __shared__ short tile[32][33];
    int s0 = blockIdx.x * 32, c0 = blockIdx.y * 32;
    int tx = threadIdx.x, ty = threadIdx.y;
    #pragma unroll
    for (int i = 0; i < 32; i += 8)
        tile[ty + i][tx] = in[(long)(s0 + ty + i) * KV_D + c0 + tx];
    __syncthreads();
    // storage position p holds key pi(p): p=g*8+j -> j<4: g*4+j ; j>=4: 16+g*4+(j-4)
    int pc = tx;
    int srckey = (pc & 4) ? (16 + (pc >> 3) * 4 + (pc & 3))
                          : ((pc >> 3) * 4 + (pc & 3));
    #pragma unroll
    for (int i = 0; i < 32; i += 8) {
        int dcol = c0 + ty + i;
        int kvh = dcol >> 6, d = dcol & 63;
        out[((long)kvh * HEAD_D + d) * SEQ + s0 + pc] = tile[srckey][ty + i];
    }
}

// ---------------- split-precision GEMM: C = (A0+A1+A2)(B0+B1+B2)^T + bias ---------------------
// OMODE 0: f32 out (+res). OMODE 2: fused QKV column routing -> q planes / k planes / vb planes.
// LDS chunk-XOR swizzled (both sides): kills the 8-way bank conflict of 64B-stride rows.
template<int OMODE, bool RES>
__global__ __launch_bounds__(256) void gemm_split(
    const short* __restrict__ A0, const short* __restrict__ A1, const short* __restrict__ A2,
    const short* __restrict__ B0, const short* __restrict__ B1, const short* __restrict__ B2,
    const float* __restrict__ bias,
    short* __restrict__ O0, short* __restrict__ O1, short* __restrict__ O2,
    short* __restrict__ K0, short* __restrict__ K1, short* __restrict__ K2,
    short* __restrict__ V0, short* __restrict__ V1, short* __restrict__ V2,
    float* __restrict__ Of, const float* __restrict__ res,
    int M, int N, int K)
{
    __shared__ short As[3][128 * 32];
    __shared__ short Bs[3][128 * 32];
    int tid = threadIdx.x;
    int lane = tid & 63, wid = tid >> 6;
    int wr = (wid >> 1) * 64, wc = (wid & 1) * 64;
    int m0 = blockIdx.x * 128, n0 = blockIdx.y * 128;

    long aoff[2]; long boff[2];
    #pragma unroll
    for (int c = 0; c < 2; c++) {
        int ch = c * 256 + tid;
        int row = ch >> 2;
        int seg = ((ch & 3) ^ swz4(row)) * 8;   // inverse-swizzled global source
        aoff[c] = (long)(m0 + row) * K + seg;
        boff[c] = (long)(n0 + row) * K + seg;
    }
    f32x4 acc[4][4];
    #pragma unroll
    for (int i = 0; i < 4; i++)
      #pragma unroll
      for (int j = 0; j < 4; j++) acc[i][j] = (f32x4){0.f, 0.f, 0.f, 0.f};

    int r = lane & 15, g = lane >> 4;
    const int kiters = K >> 5;
    const short* Ap[3] = {A0, A1, A2};
    const short* Bp[3] = {B0, B1, B2};
    for (int kt = 0; kt < kiters; kt++) {
        int k0 = kt << 5;
        #pragma unroll
        for (int p = 0; p < 3; p++) {
            #pragma unroll
            for (int c = 0; c < 2; c++) {
                GLOAD_LDS16(Ap[p] + aoff[c] + k0, &As[p][(c * 256 + tid) * 8]);
                GLOAD_LDS16(Bp[p] + boff[c] + k0, &Bs[p][(c * 256 + tid) * 8]);
            }
        }
        __syncthreads();
        bf16x8 af[3][4], bfr[3][4];
        #pragma unroll
        for (int p = 0; p < 3; p++)
          #pragma unroll
          for (int i = 0; i < 4; i++) {
            int ra = wr + i * 16 + r, rb = wc + i * 16 + r;
            af[p][i]  = *(const bf16x8*)(&As[p][ra * 32 + (g ^ swz4(ra)) * 8]);
            bfr[p][i] = *(const bf16x8*)(&Bs[p][rb * 32 + (g ^ swz4(rb)) * 8]);
          }
        #pragma unroll
        for (int i = 0; i < 4; i++)
          #pragma unroll
          for (int j = 0; j < 4; j++) {
            f32x4 a = acc[i][j];
            a = MFMA16x16x32(af[0][i], bfr[0][j], a);
            a = MFMA16x16x32(af[0][i], bfr[1][j], a);
            a = MFMA16x16x32(af[1][i], bfr[0][j], a);
            a = MFMA16x16x32(af[0][i], bfr[2][j], a);
            a = MFMA16x16x32(af[1][i], bfr[1][j], a);
            a = MFMA16x16x32(af[2][i], bfr[0][j], a);
            acc[i][j] = a;
          }
        __syncthreads();
    }
    #pragma unroll
    for (int i = 0; i < 4; i++) {
      #pragma unroll
      for (int j = 0; j < 4; j++) {
        #pragma unroll
        for (int qq = 0; qq < 4; qq++) {
            long row = m0 + wr + i * 16 + g * 4 + qq;
            int col = n0 + wc + j * 16 + r;
            float v = acc[i][j][qq] + bias[col];
            if (OMODE == 0) {
                long oi = row * N + col;
                if (RES) v += res[oi];
                Of[oi] = v;
            } else {
                short a, b_, c;
                split3(v, a, b_, c);
                if (col < 1024) {
                    long oi = row * 1024 + col;
                    O0[oi] = a; O1[oi] = b_; O2[oi] = c;
                } else if (col < 1280) {
                    long oi = row * 256 + (col - 1024);
                    K0[oi] = a; K1[oi] = b_; K2[oi] = c;
                } else {
                    long oi = row * 256 + (col - 1280);
                    V0[oi] = a; V1[oi] = b_; V2[oi] = c;
                }
            }
        }
      }
    }
}

// ---------------- bf16 MoE GEMM: 128x128 tile, 2-phase dbuf (__syncthreads), XOR swizzle ------
template<bool MOE, bool GELU, bool OUTF32>
__global__ __launch_bounds__(256) void gemm_bt(
    const short* __restrict__ A, const short* __restrict__ Bt,
    const float* __restrict__ bias, void* __restrict__ Cout,
    int M, int N, int K,
    const int* __restrict__ counts, const int* __restrict__ bases,
    long bt_estride, int bias_estride)
{
    int cnt = M, rowbase = 0;
    if (MOE) {
        int e = blockIdx.z;
        cnt = counts[e];
        if ((int)blockIdx.x * 128 >= cnt) return;
        rowbase = bases[e];
        Bt += (long)e * bt_estride;
        bias += (long)e * bias_estride;
    }
    __shared__ short As[2][128 * 32];
    __shared__ short Bs[2][128 * 32];
    int tid = threadIdx.x;
    int lane = tid & 63, wid = tid >> 6;
    int wr = (wid >> 1) * 64, wc = (wid & 1) * 64;
    int m0 = blockIdx.x * 128, n0 = blockIdx.y * 128;

    long aoff[2]; long boff[2];
    #pragma unroll
    for (int c = 0; c < 2; c++) {
        int ch = c * 256 + tid;
        int row = ch >> 2;
        int seg = ((ch & 3) ^ swz4(row)) * 8;   // inverse-swizzled global source
        int grow = m0 + row;
        long rowidx;
        if (MOE) rowidx = rowbase + (grow < cnt ? grow : 0);
        else     rowidx = grow;
        aoff[c] = rowidx * (long)K + seg;
        boff[c] = (long)(n0 + row) * K + seg;
    }
    f32x4 acc[4][4];
    #pragma unroll
    for (int i = 0; i < 4; i++)
      #pragma unroll
      for (int j = 0; j < 4; j++) acc[i][j] = (f32x4){0.f, 0.f, 0.f, 0.f};

    int r = lane & 15, g = lane >> 4;
    const int kiters = K >> 5;

    auto stage = [&](int buf, int k0) {
        #pragma unroll
        for (int c = 0; c < 2; c++) {
            GLOAD_LDS16(A + aoff[c] + k0, &As[buf][(c * 256 + tid) * 8]);
            GLOAD_LDS16(Bt + boff[c] + k0, &Bs[buf][(c * 256 + tid) * 8]);
        }
    };

    stage(0, 0);
    __syncthreads();

    for (int kt = 0; kt < kiters; kt++) {
        int cur = kt & 1;
        if (kt + 1 < kiters) stage(cur ^ 1, (kt + 1) << 5);
        bf16x8 af[4], bfr[4];
        #pragma unroll
        for (int i = 0; i < 4; i++) {
            int ra = wr + i * 16 + r;
            af[i] = *(const bf16x8*)(&As[cur][ra * 32 + (g ^ swz4(ra)) * 8]);
        }
        #pragma unroll
        for (int j = 0; j < 4; j++) {
            int rb = wc + j * 16 + r;
            bfr[j] = *(const bf16x8*)(&Bs[cur][rb * 32 + (g ^ swz4(rb)) * 8]);
        }
        #pragma unroll
        for (int i = 0; i < 4; i++)
          #pragma unroll
          for (int j = 0; j < 4; j++)
            acc[i][j] = MFMA16x16x32(af[i], bfr[j], acc[i][j]);
        __syncthreads();
    }
    #pragma unroll
    for (int i = 0; i < 4; i++) {
      #pragma unroll
      for (int j = 0; j < 4; j++) {
        #pragma unroll
        for (int qq = 0; qq < 4; qq++) {
            int row = m0 + wr + i * 16 + g * 4 + qq;
            if (MOE && row >= cnt) continue;
            int col = n0 + wc + j * 16 + r;
            float v = acc[i][j][qq] + bias[col];
            if (GELU) v = 0.5f * v * (1.0f + erff(v * 0.70710678118f));
            long orow = MOE ? (long)(rowbase + row) : (long)row;
            if (OUTF32) ((float*)Cout)[orow * N + col] = v;
            else        ((short*)Cout)[orow * N + col] = f2bf(v);
        }
      }
    }
}

// ---------------- token gather: xg[pos] = src[gidx[pos]] (coalesced 16B lanes) ----------------
__global__ __launch_bounds__(256) void gather_kernel(const short* __restrict__ src,
    const int* __restrict__ gidx, short* __restrict__ dst)
{
    long idx = (long)blockIdx.x * 256 + threadIdx.x;
    int row = (int)(idx >> 7);
    int c = (int)(idx & 127);
    int t = gidx[row];
    *(bf16x8*)(dst + (size_t)row * D_MODEL + c * 8) =
        *(const bf16x8*)(src + (size_t)t * D_MODEL + c * 8);
}

// ---------------- split-precision flash attention: LDS-staged K/V, register P -----------------
__global__ __launch_bounds__(256) void attn_split(
    const short* __restrict__ q0p, const short* __restrict__ q1p, const short* __restrict__ q2p,
    const short* __restrict__ k0p, const short* __restrict__ k1p, const short* __restrict__ k2p,
    const short* __restrict__ v0p, const short* __restrict__ v1p, const short* __restrict__ v2p,
    short* __restrict__ ao0, short* __restrict__ ao1, short* __restrict__ ao2)
{
    __shared__ short lds[2][2][3][2048];   // [buf][K/V][plane][4KB]
    int tid = threadIdx.x;
    int wid = tid >> 6, lane = tid & 63;
    int r = lane & 15, g = lane >> 4;
    int bh = blockIdx.y;
    int b = bh >> 4, h = bh & 15, kvh = h >> 2;
    int q0_ = blockIdx.x * 64 + wid * 16;

    size_t qoff = ((size_t)(b * SEQ + q0_ + r)) * D_MODEL + h * HEAD_D + g * 8;
    bf16x8 qf[3][2];
    qf[0][0] = *(const bf16x8*)(q0p + qoff); qf[0][1] = *(const bf16x8*)(q0p + qoff + 32);
    qf[1][0] = *(const bf16x8*)(q1p + qoff); qf[1][1] = *(const bf16x8*)(q1p + qoff + 32);
    qf[2][0] = *(const bf16x8*)(q2p + qoff); qf[2][1] = *(const bf16x8*)(q2p + qoff + 32);

    size_t kbo = (size_t)(b * SEQ) * KV_D + kvh * HEAD_D;
    const short* kb[3] = {k0p + kbo, k1p + kbo, k2p + kbo};
    size_t vbo = (size_t)((b * N_KV + kvh) * HEAD_D) * SEQ;
    const short* vtp[3] = {v0p + vbo, v1p + vbo, v2p + vbo};

    int krow = tid >> 3;
    int ksrc = ((tid & 7) * 16) ^ ((krow & 7) << 4);
    int vrow = tid >> 2;
    int vsrc = ((tid & 3) * 16) ^ (((vrow >> 1) & 3) << 4);

    auto stage = [&](int buf, int kt) {
        int key0 = kt * 32;
        #pragma unroll
        for (int p = 0; p < 3; p++) {
            const short* src = kb[p] + (size_t)(key0 + krow) * KV_D + (ksrc >> 1);
            GLOAD_LDS16(src, &lds[buf][0][p][tid * 8]);
        }
        #pragma unroll
        for (int p = 0; p < 3; p++) {
            const short* src = vtp[p] + (size_t)vrow * SEQ + key0 + (vsrc >> 1);
            GLOAD_LDS16(src, &lds[buf][1][p][tid * 8]);
        }
    };

    float m_run = -1e30f, lsum = 0.f;
    f32x4 o[4];
    #pragma unroll
    for (int i = 0; i < 4; i++) o[i] = (f32x4){0.f, 0.f, 0.f, 0.f};

    stage(0, 0);
    __syncthreads();

    for (int kt = 0; kt < SEQ / 32; kt++) {
        int cur = kt & 1;
        if (kt < SEQ / 32 - 1) stage(cur ^ 1, kt + 1);

        f32x4 sT0, sT1;
        #pragma unroll
        for (int kh = 0; kh < 2; kh++) {
            f32x4 s = (f32x4){0.f, 0.f, 0.f, 0.f};
            #pragma unroll
            for (int c = 0; c < 2; c++) {
                int koff = ((kh * 16 + r) * 128 + ((c * 64 + g * 16) ^ ((r & 7) << 4))) >> 1;
                bf16x8 k0f = *(const bf16x8*)(&lds[cur][0][0][koff]);
                bf16x8 k1f = *(const bf16x8*)(&lds[cur][0][1][koff]);
                bf16x8 k2f = *(const bf16x8*)(&lds[cur][0][2][koff]);
                s = MFMA16x16x32(k0f, qf[0][c], s);
                s = MFMA16x16x32(k1f, qf[0][c], s);
                s = MFMA16x16x32(k0f, qf[1][c], s);
                s = MFMA16x16x32(k2f, qf[0][c], s);
                s = MFMA16x16x32(k1f, qf[1][c], s);
                s = MFMA16x16x32(k0f, qf[2][c], s);
            }
            if (kh == 0) sT0 = s; else sT1 = s;
        }

        float a0[4], a1[4];
        float vmx = -1e30f;
        #pragma unroll
        for (int rr = 0; rr < 4; rr++) {
            a0[rr] = sT0[rr] * 0.125f;
            a1[rr] = sT1[rr] * 0.125f;
            vmx = fmaxf(vmx, fmaxf(a0[rr], a1[rr]));
        }
        vmx = fmaxf(vmx, __shfl_xor(vmx, 16));
        vmx = fmaxf(vmx, __shfl_xor(vmx, 32));
        float mn = fmaxf(m_run, vmx);
        float alpha = __expf(m_run - mn);
        m_run = mn;
        float p0[4], p1[4], ps = 0.f;
        #pragma unroll
        for (int rr = 0; rr < 4; rr++) {
            p0[rr] = __expf(a0[rr] - mn);
            p1[rr] = __expf(a1[rr] - mn);
            ps += p0[rr] + p1[rr];
        }
        ps += __shfl_xor(ps, 16);
        ps += __shfl_xor(ps, 32);
        lsum = lsum * alpha + ps;
        bf16x8 pw0, pw1, pw2;
        #pragma unroll
        for (int rr = 0; rr < 4; rr++) {
            short h0_, m0_, l0_, h1_, m1_, l1_;
            split3(p0[rr], h0_, m0_, l0_);
            split3(p1[rr], h1_, m1_, l1_);
            pw0[rr] = h0_; pw0[4 + rr] = h1_;
            pw1[rr] = m0_; pw1[4 + rr] = m1_;
            pw2[rr] = l0_; pw2[4 + rr] = l1_;
        }
        float af[4];
        #pragma unroll
        for (int rr = 0; rr < 4; rr++) af[rr] = __shfl(alpha, g * 4 + rr);
        #pragma unroll
        for (int fc = 0; fc < 4; fc++)
          #pragma unroll
          for (int rr = 0; rr < 4; rr++) o[fc][rr] *= af[rr];

        #pragma unroll
        for (int fc = 0; fc < 4; fc++) {
            int voff = ((fc * 16 + r) * 64 + ((g * 16) ^ (((r >> 1) & 3) << 4))) >> 1;
            bf16x8 bv0 = *(const bf16x8*)(&lds[cur][1][0][voff]);
            bf16x8 bv1 = *(const bf16x8*)(&lds[cur][1][1][voff]);
            bf16x8 bv2 = *(const bf16x8*)(&lds[cur][1][2][voff]);
            f32x4 a = o[fc];
            a = MFMA16x16x32(pw0, bv0, a);
            a = MFMA16x16x32(pw0, bv1, a);
            a = MFMA16x16x32(pw1, bv0, a);
            a = MFMA16x16x32(pw0, bv2, a);
            a = MFMA16x16x32(pw1, bv1, a);
            a = MFMA16x16x32(pw2, bv0, a);
            o[fc] = a;
        }

        __syncthreads();
    }

    float linv[4];
    #pragma unroll
    for (int rr = 0; rr < 4; rr++) linv[rr] = 1.0f / __shfl(lsum, g * 4 + rr);
    #pragma unroll
    for (int fc = 0; fc < 4; fc++) {
        #pragma unroll
        for (int rr = 0; rr < 4; rr++) {
            float v = o[fc][rr] * linv[rr];
            int qrow = q0_ + g * 4 + rr;
            int col = h * HEAD_D + fc * 16 + r;
            size_t oi = ((size_t)(b * SEQ + qrow)) * D_MODEL + col;
            short a_, b_, c_;
            split3(v, a_, b_, c_);
            ao0[oi] = a_; ao1[oi] = b_; ao2[oi] = c_;
        }
    }
}

// ---------------- router (f32 exact, no atomics) ----------------------------------------------
__global__ __launch_bounds__(256) void router_kernel(
    const float* __restrict__ h2f, const float* __restrict__ Wr, const float* __restrict__ br,
    int* __restrict__ topi, float* __restrict__ topw)
{
    int wid = threadIdx.x >> 6, lane = threadIdx.x & 63;
    int t = blockIdx.x * 4 + wid;
    const float4* hr = (const float4*)(h2f + (size_t)t * D_MODEL + lane * 16);
    float acc[8] = {0.f,0.f,0.f,0.f,0.f,0.f,0.f,0.f};
    #pragma unroll
    for (int ii = 0; ii < 4; ii++) {
        float4 hv4 = hr[ii];
        float hv[4] = {hv4.x, hv4.y, hv4.z, hv4.w};
        #pragma unroll
        for (int c = 0; c < 4; c++) {
            int idx = lane * 16 + ii * 4 + c;
            const float4* w4 = (const float4*)(Wr + (size_t)idx * 8);
            float4 w0 = w4[0], w1 = w4[1];
            acc[0] += hv[c] * w0.x; acc[1] += hv[c] * w0.y;
            acc[2] += hv[c] * w0.z; acc[3] += hv[c] * w0.w;
            acc[4] += hv[c] * w1.x; acc[5] += hv[c] * w1.y;
            acc[6] += hv[c] * w1.z; acc[7] += hv[c] * w1.w;
        }
    }
    #pragma unroll
    for (int e = 0; e < 8; e++) {
        float v = acc[e];
        #pragma unroll
        for (int o = 32; o > 0; o >>= 1) v += __shfl_xor(v, o);
        acc[e] = v + br[e];
    }
    if (lane == 0) {
        int i0 = 0; float l0 = acc[0];
        #pragma unroll
        for (int e = 1; e < 8; e++) if (acc[e] > l0) { l0 = acc[e]; i0 = e; }
        int i1 = -1; float l1 = -1e30f;
        #pragma unroll
        for (int e = 0; e < 8; e++) if (e != i0 && acc[e] > l1) { l1 = acc[e]; i1 = e; }
        float e1 = expf(l1 - l0);
        float w0 = 1.0f / (1.0f + e1);
        topi[t * 2] = i0; topi[t * 2 + 1] = i1;
        topw[t * 2] = w0; topw[t * 2 + 1] = e1 * w0;
    }
}

// ---------------- histogram + prefix (1 block) ------------------------------------------------
__global__ __launch_bounds__(1024) void hist_kernel(const int* __restrict__ topi,
    int* __restrict__ counts, int* __restrict__ bases, int* __restrict__ cursor)
{
    __shared__ int hc[8];
    int tid = threadIdx.x;
    if (tid < 8) hc[tid] = 0;
    __syncthreads();
    int c[8] = {0,0,0,0,0,0,0,0};
    for (int i = tid; i < 2 * T_TOK; i += 1024) {
        int e = topi[i];
        #pragma unroll
        for (int q = 0; q < 8; q++) c[q] += (e == q) ? 1 : 0;
    }
    #pragma unroll
    for (int e = 0; e < 8; e++) {
        int v = c[e];
        #pragma unroll
        for (int o = 32; o > 0; o >>= 1) v += __shfl_xor(v, o);
        if ((tid & 63) == 0) atomicAdd(&hc[e], v);
    }
    __syncthreads();
    if (tid == 0) {
        int s = 0;
        #pragma unroll
        for (int e = 0; e < 8; e++) { bases[e] = s; counts[e] = hc[e]; s += hc[e]; }
    }
    if (tid >= 64 && tid < 72) cursor[tid - 64] = 0;
}

// ---------------- assign with wave-aggregated atomics -----------------------------------------
__global__ __launch_bounds__(256) void assign_kernel(const int* __restrict__ topi,
    const int* __restrict__ bases, int* __restrict__ cursor,
    int* __restrict__ gidx, int* __restrict__ pos_of)
{
    int t = blockIdx.x * 256 + threadIdx.x;
    int lane = threadIdx.x & 63;
    #pragma unroll
    for (int kk = 0; kk < 2; kk++) {
        int e = topi[t * 2 + kk];
        #pragma unroll
        for (int e8 = 0; e8 < 8; e8++) {
            bool mine = (e == e8);
            unsigned long long m = __ballot(mine);
            if (m == 0ull) continue;
            int lead = __ffsll((long long)m) - 1;
            int base = 0;
            if (lane == lead) base = atomicAdd(&cursor[e8], __popcll(m));
            base = __shfl(base, lead);
            if (mine) {
                int pos = bases[e8] + base + (int)__popcll(m & ((1ull << lane) - 1ull));
                gidx[pos] = t;
                pos_of[t * 2 + kk] = pos;
            }
        }
    }
}

__global__ void biascat_kernel(const float* __restrict__ bq, const float* __restrict__ bk,
                               const float* __restrict__ bv, float* __restrict__ out)
{
    int i = blockIdx.x * 256 + threadIdx.x;
    if (i < 1024) out[i] = bq[i];
    else if (i < 1280) out[i] = bk[i - 1024];
    else if (i < 1536) out[i] = bv[i - 1280];
}

__global__ __launch_bounds__(256) void combine_kernel(const float* __restrict__ x2,
    const float* __restrict__ y, const int* __restrict__ pos_of,
    const float* __restrict__ topw, float* __restrict__ out)
{
    long idx = (long)blockIdx.x * 256 + threadIdx.x;
    int t = (int)(idx >> 8);
    int c = (int)(idx & 255);
    int p0 = pos_of[t * 2], p1 = pos_of[t * 2 + 1];
    float w0 = topw[t * 2], w1 = topw[t * 2 + 1];
    float4 a = ((const float4*)(x2 + (size_t)t * D_MODEL))[c];
    float4 u = ((const float4*)(y + (size_t)p0 * D_MODEL))[c];
    float4 v = ((const float4*)(y + (size_t)p1 * D_MODEL))[c];
    float4 o;
    o.x = a.x + w0 * u.x + w1 * v.x;
    o.y = a.y + w0 * u.y + w1 * v.y;
    o.z = a.z + w0 * u.z + w1 * v.z;
    o.w = a.w + w0 * u.w + w1 * v.w;
    ((float4*)(out + (size_t)t * D_MODEL))[c] = o;
}

extern "C" void kernel_launch(void* const* d_in, const int* in_sizes, int n_in,
                              void* d_out, int out_size, void* d_ws, size_t ws_size,
                              hipStream_t stream)
{
    (void)in_sizes; (void)n_in; (void)out_size; (void)ws_size;
    const float* x   = (const float*)d_in[0];
    const float* Wq  = (const float*)d_in[1];
    const float* bq  = (const float*)d_in[2];
    const float* Wk  = (const float*)d_in[3];
    const float* bk  = (const float*)d_in[4];
    const float* Wv  = (const float*)d_in[5];
    const float* bv  = (const float*)d_in[6];
    const float* Wo  = (const float*)d_in[7];
    const float* bo  = (const float*)d_in[8];
    const float* g1  = (const float*)d_in[9];
    const float* b1n = (const float*)d_in[10];
    const float* g2  = (const float*)d_in[11];
    const float* b2n = (const float*)d_in[12];
    const float* Wr  = (const float*)d_in[13];
    const float* br  = (const float*)d_in[14];
    const float* W1  = (const float*)d_in[15];
    const float* b1e = (const float*)d_in[16];
    const float* W2  = (const float*)d_in[17];
    const float* b2e = (const float*)d_in[18];
    float* out = (float*)d_out;

    size_t off = 0;
    auto alloc = [&](size_t n) {
        size_t cur = off;
        off = (cur + n + 255) & ~(size_t)255;
        return (void*)((char*)d_ws + cur);
    };
    const size_t PD = (size_t)T_TOK * D_MODEL;
    const size_t PK = (size_t)T_TOK * KV_D;
    const size_t WQKV = (size_t)1536 * 1024;
    const size_t WQP  = (size_t)D_MODEL * D_MODEL;
    short* blkA   = (short*)alloc(3 * PD * 2);       // h planes -> ao planes -> xg (aliased)
    short* blkB   = (short*)alloc(3 * PD * 2);       // q planes -> h2hi + h2f
    short* kpl    = (short*)alloc(3 * PK * 2);
    short* vbpl   = (short*)alloc(3 * PK * 2);
    short* vtpl   = (short*)alloc(3 * PK * 2);
    float* x2     = (float*)alloc(PD * 4);
    short* WqkvT3 = (short*)alloc(3 * WQKV * 2);
    short* WoT3   = (short*)alloc(3 * WQP * 2);
    float* bqkv   = (float*)alloc(1536 * 4);
    short* W1T    = (short*)alloc((size_t)N_EXP * H_FF * D_MODEL * 2);
    short* W2T    = (short*)alloc((size_t)N_EXP * D_MODEL * H_FF * 2);
    short* mid    = (short*)alloc((size_t)(2 * T_TOK) * H_FF * 2);
    float* yb     = (float*)alloc((size_t)(2 * T_TOK) * D_MODEL * 4);
    int* counts = (int*)alloc(256);
    int* bases  = (int*)alloc(256);
    int* cursor = (int*)alloc(256);
    int* topi   = (int*)alloc((size_t)T_TOK * 2 * 4);
    float* topw = (float*)alloc((size_t)T_TOK * 2 * 4);
    int* posof  = (int*)alloc((size_t)T_TOK * 2 * 4);
    int* gidx   = (int*)alloc((size_t)2 * T_TOK * 4);

    short* h0 = blkA, *h1 = blkA + PD, *h2p = blkA + 2 * PD;
    short* ao0 = blkA, *ao1 = blkA + PD, *ao2 = blkA + 2 * PD;
    short* xg = blkA;   // alias: blkA (h/ao planes) is dead after the O-projection;
                        // gather (32 MiB) runs strictly later.
    short* q0 = blkB, *q1 = blkB + PD, *q2 = blkB + 2 * PD;
    short* h2hi = blkB;
    float* h2f = (float*)(blkB + PD);
    short* k0 = kpl, *k1 = kpl + PK, *k2 = kpl + 2 * PK;
    short* vb0 = vbpl, *vb1 = vbpl + PK, *vb2 = vbpl + 2 * PK;
    short* vt0 = vtpl, *vt1 = vtpl + PK, *vt2 = vtpl + 2 * PK;

    dim3 tb(32, 8);
    transpose_f2b3<<<dim3(32, 32), tb, 0, stream>>>(Wq, WqkvT3,                   (long)WQKV, 1024, 1024);
    transpose_f2b3<<<dim3(8, 32),  tb, 0, stream>>>(Wk, WqkvT3 + (size_t)1024 * 1024, (long)WQKV, 1024, 256);
    transpose_f2b3<<<dim3(8, 32),  tb, 0, stream>>>(Wv, WqkvT3 + (size_t)1280 * 1024, (long)WQKV, 1024, 256);
    transpose_f2b3<<<dim3(32, 32), tb, 0, stream>>>(Wo, WoT3, (long)WQP, 1024, 1024);
    transpose_f2b<<<dim3(128, 32, 8), tb, 0, stream>>>(W1, W1T, 1024, 4096,
        (long)1024 * 4096, (long)4096 * 1024);
    transpose_f2b<<<dim3(32, 128, 8), tb, 0, stream>>>(W2, W2T, 4096, 1024,
        (long)4096 * 1024, (long)1024 * 4096);
    biascat_kernel<<<6, 256, 0, stream>>>(bq, bk, bv, bqkv);

    ln_kernel<0><<<T_TOK, 256, 0, stream>>>(x, g1, b1n, h0, h1, h2p, nullptr);

    // fused QKV projection
    gemm_split<2, false><<<dim3(64, 12), 256, 0, stream>>>(
        h0, h1, h2p, WqkvT3, WqkvT3 + WQKV, WqkvT3 + 2 * WQKV, bqkv,
        q0, q1, q2, k0, k1, k2, vb0, vb1, vb2,
        nullptr, nullptr, T_TOK, 1536, 1024);

    vperm_kernel<<<dim3(32, 8, 24), tb, 0, stream>>>(vbpl, vtpl, (long)PK, (long)PK);

    attn_split<<<dim3(16, 128), 256, 0, stream>>>(q0, q1, q2, k0, k1, k2,
        vt0, vt1, vt2, ao0, ao1, ao2);

    gemm_split<0, true><<<dim3(64, 8), 256, 0, stream>>>(
        ao0, ao1, ao2, WoT3, WoT3 + WQP, WoT3 + 2 * WQP, bo,
        nullptr, nullptr, nullptr, nullptr, nullptr, nullptr, nullptr, nullptr, nullptr,
        x2, x, T_TOK, 1024, 1024);

    ln_kernel<1><<<T_TOK, 256, 0, stream>>>(x2, g2, b2n, h2hi, nullptr, nullptr, h2f);

    router_kernel<<<2048, 256, 0, stream>>>(h2f, Wr, br, topi, topw);
    hist_kernel<<<1, 1024, 0, stream>>>(topi, counts, bases, cursor);
    assign_kernel<<<32, 256, 0, stream>>>(topi, bases, cursor, gidx, posof);
    gather_kernel<<<8192, 256, 0, stream>>>(h2hi, gidx, xg);

    gemm_bt<true, true, false><<<dim3(64, 32, 8), 256, 0, stream>>>(
        xg, W1T, b1e, mid, 0, 4096, 1024, counts, bases,
        (long)H_FF * D_MODEL, H_FF);
    gemm_bt<true, false, true><<<dim3(64, 8, 8), 256, 0, stream>>>(
        mid, W2T, b2e, yb, 0, 1024, 4096, counts, bases,
        (long)D_MODEL * H_FF, D_MODEL);

    combine_kernel<<<8192, 256, 0, stream>>>(x2, yb, posof, topw, out);
}

// Round 12
// 1266.983 us; speedup vs baseline: 1.8981x; 1.2490x over previous
//
#include <hip/hip_runtime.h>
#include <hip/hip_bf16.h>

#define T_TOK 8192
#define D_MODEL 1024
#define N_HEADS 16
#define N_KV 4
#define HEAD_D 64
#define SEQ 1024
#define BATCH 8
#define N_EXP 8
#define H_FF 4096
#define KV_D 256

typedef __attribute__((ext_vector_type(8))) short bf16x8;
typedef __attribute__((ext_vector_type(4))) float f32x4;
typedef __attribute__((ext_vector_type(4))) short s16x4;

__device__ __forceinline__ float bf2f(short s) {
    union { unsigned u; float f; } v; v.u = ((unsigned)(unsigned short)s) << 16; return v.f;
}
__device__ __forceinline__ short f2bf(float f) {
    union { float fl; unsigned u; } v; v.fl = f;
    unsigned r = v.u + 0x7FFFu + ((v.u >> 16) & 1u);
    return (short)(r >> 16);
}
// 3-way bf16 split: x ~= hi + mid + lo to ~2^-26 relative
__device__ __forceinline__ void split3(float x, short& a, short& b, short& c) {
    a = f2bf(x);
    float r1 = x - bf2f(a);
    b = f2bf(r1);
    float r2 = r1 - bf2f(b);
    c = f2bf(r2);
}
// chunk swizzle (kept from r11, measured neutral; not the lever)
__device__ __forceinline__ int swz4(int row) {
    return (row & 3) ^ ((row >> 2) & 3);
}

#define MFMA16x16x32(a,b,c) __builtin_amdgcn_mfma_f32_16x16x32_bf16(a,b,c,0,0,0)

#define GLOAD_LDS16(gp, lp) \
  __builtin_amdgcn_global_load_lds((const __attribute__((address_space(1))) unsigned int*)(const void*)(gp), \
                                   (__attribute__((address_space(3))) unsigned int*)(void*)(lp), 16, 0, 0)

// ---------------- LayerNorm: MODE 0 -> 3 bf16 planes; MODE 1 -> bf16 hi + f32 ----------------
template<int MODE>
__global__ __launch_bounds__(256) void ln_kernel(const float* __restrict__ x,
        const float* __restrict__ g, const float* __restrict__ b,
        short* __restrict__ o0, short* __restrict__ o1, short* __restrict__ o2,
        float* __restrict__ of)
{
    int row = blockIdx.x;
    int tid = threadIdx.x;
    const float4* xr = (const float4*)(x + (size_t)row * D_MODEL);
    float4 v = xr[tid];
    float s = v.x + v.y + v.z + v.w;
    float sq = v.x*v.x + v.y*v.y + v.z*v.z + v.w*v.w;
    #pragma unroll
    for (int o = 32; o > 0; o >>= 1) { s += __shfl_xor(s, o); sq += __shfl_xor(sq, o); }
    __shared__ float red[8];
    int wid = tid >> 6, lane = tid & 63;
    if (lane == 0) { red[wid] = s; red[4 + wid] = sq; }
    __syncthreads();
    s = red[0] + red[1] + red[2] + red[3];
    sq = red[4] + red[5] + red[6] + red[7];
    float mean = s * (1.0f / D_MODEL);
    float var = sq * (1.0f / D_MODEL) - mean * mean;
    float rstd = rsqrtf(var + 1e-5f);
    float4 gg = ((const float4*)g)[tid], bb = ((const float4*)b)[tid];
    float y[4];
    y[0] = (v.x - mean) * rstd * gg.x + bb.x;
    y[1] = (v.y - mean) * rstd * gg.y + bb.y;
    y[2] = (v.z - mean) * rstd * gg.z + bb.z;
    y[3] = (v.w - mean) * rstd * gg.w + bb.w;
    size_t o_off = (size_t)row * D_MODEL + tid * 4;
    if (MODE == 0) {
        s16x4 t0, t1, t2;
        #pragma unroll
        for (int i = 0; i < 4; i++) { short a, b_, c; split3(y[i], a, b_, c); t0[i]=a; t1[i]=b_; t2[i]=c; }
        *(s16x4*)(o0 + o_off) = t0;
        *(s16x4*)(o1 + o_off) = t1;
        *(s16x4*)(o2 + o_off) = t2;
    } else {
        s16x4 t0;
        #pragma unroll
        for (int i = 0; i < 4; i++) t0[i] = f2bf(y[i]);
        *(s16x4*)(o0 + o_off) = t0;
        float4 yo; yo.x = y[0]; yo.y = y[1]; yo.z = y[2]; yo.w = y[3];
        ((float4*)(of + (size_t)row * D_MODEL))[tid] = yo;
    }
}

// ---------------- transpose f32 [R][C] -> bf16 [C][R] (single plane, for MoE weights) ---------
__global__ void transpose_f2b(const float* __restrict__ in, short* __restrict__ out,
                              int R, int C, long in_z, long out_z)
{
    in += (long)blockIdx.z * in_z;
    out += (long)blockIdx.z * out_z;
    __shared__ float tile[32][33];
    int c0 = blockIdx.x * 32, r0 = blockIdx.y * 32;
    int tx = threadIdx.x, ty = threadIdx.y;
    #pragma unroll
    for (int i = 0; i < 32; i += 8)
        tile[ty + i][tx] = in[(long)(r0 + ty + i) * C + c0 + tx];
    __syncthreads();
    #pragma unroll
    for (int i = 0; i < 32; i += 8)
        out[(long)(c0 + ty + i) * R + r0 + tx] = f2bf(tile[tx][ty + i]);
}

// ---------------- transpose f32 [R][C] -> 3 bf16 planes [C][R], plane stride pstride ----------
__global__ void transpose_f2b3(const float* __restrict__ in, short* __restrict__ o0,
                               long pstride, int R, int C)
{
    __shared__ float tile[32][33];
    int c0 = blockIdx.x * 32, r0 = blockIdx.y * 32;
    int tx = threadIdx.x, ty = threadIdx.y;
    #pragma unroll
    for (int i = 0; i < 32; i += 8)
        tile[ty + i][tx] = in[(long)(r0 + ty + i) * C + c0 + tx];
    __syncthreads();
    #pragma unroll
    for (int i = 0; i < 32; i += 8) {
        long oi = (long)(c0 + ty + i) * R + r0 + tx;
        short a, b_, c;
        split3(tile[tx][ty + i], a, b_, c);
        o0[oi] = a; o0[oi + pstride] = b_; o0[oi + 2 * pstride] = c;
    }
}

// ---------------- V transpose + PV key-permutation bake: vb[b][s][256] -> vt[b][kvh][d][key'] -
__global__ void vperm_kernel(const short* __restrict__ in, short* __restrict__ out,
                             long in_pstride, long out_pstride)
{
    int p = blockIdx.z >> 3;
    int b = blockIdx.z & 7;
    in  += p * in_pstride  + (long)b * SEQ * KV_D;
    out += p * out_pstride + (long)b * N_KV * HEAD_D * SEQ;
    __shared__ short tile[32][33];
    int s0 = blockIdx.x * 32, c0 = blockIdx.y * 32;
    int tx = threadIdx.x, ty = threadIdx.y;
    #pragma unroll
    for (int i = 0; i < 32; i += 8)
        tile[ty + i][tx] = in[(long)(s0 + ty + i) * KV_D + c0 + tx];
    __syncthreads();
    // storage position p holds key pi(p): p=g*8+j -> j<4: g*4+j ; j>=4: 16+g*4+(j-4)
    int pc = tx;
    int srckey = (pc & 4) ? (16 + (pc >> 3) * 4 + (pc & 3))
                          : ((pc >> 3) * 4 + (pc & 3));
    #pragma unroll
    for (int i = 0; i < 32; i += 8) {
        int dcol = c0 + ty + i;
        int kvh = dcol >> 6, d = dcol & 63;
        out[((long)kvh * HEAD_D + d) * SEQ + s0 + pc] = tile[srckey][ty + i];
    }
}

// ---------------- split-precision GEMM: C = (A0+A1+A2)(B0+B1+B2)^T + bias ---------------------
// OMODE 0: f32 out (+res). OMODE 2: fused QKV column routing -> q planes / k planes / vb planes.
template<int OMODE, bool RES>
__global__ __launch_bounds__(256) void gemm_split(
    const short* __restrict__ A0, const short* __restrict__ A1, const short* __restrict__ A2,
    const short* __restrict__ B0, const short* __restrict__ B1, const short* __restrict__ B2,
    const float* __restrict__ bias,
    short* __restrict__ O0, short* __restrict__ O1, short* __restrict__ O2,
    short* __restrict__ K0, short* __restrict__ K1, short* __restrict__ K2,
    short* __restrict__ V0, short* __restrict__ V1, short* __restrict__ V2,
    float* __restrict__ Of, const float* __restrict__ res,
    int M, int N, int K)
{
    __shared__ short As[3][128 * 32];
    __shared__ short Bs[3][128 * 32];
    int tid = threadIdx.x;
    int lane = tid & 63, wid = tid >> 6;
    int wr = (wid >> 1) * 64, wc = (wid & 1) * 64;
    int m0 = blockIdx.x * 128, n0 = blockIdx.y * 128;

    long aoff[2]; long boff[2];
    #pragma unroll
    for (int c = 0; c < 2; c++) {
        int ch = c * 256 + tid;
        int row = ch >> 2;
        int seg = ((ch & 3) ^ swz4(row)) * 8;   // inverse-swizzled global source
        aoff[c] = (long)(m0 + row) * K + seg;
        boff[c] = (long)(n0 + row) * K + seg;
    }
    f32x4 acc[4][4];
    #pragma unroll
    for (int i = 0; i < 4; i++)
      #pragma unroll
      for (int j = 0; j < 4; j++) acc[i][j] = (f32x4){0.f, 0.f, 0.f, 0.f};

    int r = lane & 15, g = lane >> 4;
    const int kiters = K >> 5;
    const short* Ap[3] = {A0, A1, A2};
    const short* Bp[3] = {B0, B1, B2};
    for (int kt = 0; kt < kiters; kt++) {
        int k0 = kt << 5;
        #pragma unroll
        for (int p = 0; p < 3; p++) {
            #pragma unroll
            for (int c = 0; c < 2; c++) {
                GLOAD_LDS16(Ap[p] + aoff[c] + k0, &As[p][(c * 256 + tid) * 8]);
                GLOAD_LDS16(Bp[p] + boff[c] + k0, &Bs[p][(c * 256 + tid) * 8]);
            }
        }
        __syncthreads();
        bf16x8 af[3][4], bfr[3][4];
        #pragma unroll
        for (int p = 0; p < 3; p++)
          #pragma unroll
          for (int i = 0; i < 4; i++) {
            int ra = wr + i * 16 + r, rb = wc + i * 16 + r;
            af[p][i]  = *(const bf16x8*)(&As[p][ra * 32 + (g ^ swz4(ra)) * 8]);
            bfr[p][i] = *(const bf16x8*)(&Bs[p][rb * 32 + (g ^ swz4(rb)) * 8]);
          }
        #pragma unroll
        for (int i = 0; i < 4; i++)
          #pragma unroll
          for (int j = 0; j < 4; j++) {
            f32x4 a = acc[i][j];
            a = MFMA16x16x32(af[0][i], bfr[0][j], a);
            a = MFMA16x16x32(af[0][i], bfr[1][j], a);
            a = MFMA16x16x32(af[1][i], bfr[0][j], a);
            a = MFMA16x16x32(af[0][i], bfr[2][j], a);
            a = MFMA16x16x32(af[1][i], bfr[1][j], a);
            a = MFMA16x16x32(af[2][i], bfr[0][j], a);
            acc[i][j] = a;
          }
        __syncthreads();
    }
    #pragma unroll
    for (int i = 0; i < 4; i++) {
      #pragma unroll
      for (int j = 0; j < 4; j++) {
        #pragma unroll
        for (int qq = 0; qq < 4; qq++) {
            long row = m0 + wr + i * 16 + g * 4 + qq;
            int col = n0 + wc + j * 16 + r;
            float v = acc[i][j][qq] + bias[col];
            if (OMODE == 0) {
                long oi = row * N + col;
                if (RES) v += res[oi];
                Of[oi] = v;
            } else {
                short a, b_, c;
                split3(v, a, b_, c);
                if (col < 1024) {
                    long oi = row * 1024 + col;
                    O0[oi] = a; O1[oi] = b_; O2[oi] = c;
                } else if (col < 1280) {
                    long oi = row * 256 + (col - 1024);
                    K0[oi] = a; K1[oi] = b_; K2[oi] = c;
                } else {
                    long oi = row * 256 + (col - 1280);
                    V0[oi] = a; V1[oi] = b_; V2[oi] = c;
                }
            }
        }
      }
    }
}

// ---------------- bf16 MoE GEMM: 128x128 tile, 2-phase dbuf, T1 bijective XCD chunking --------
// Block remap (m204): hardware assigns XCD = linear_id % 8 round-robin. Remap so each XCD owns
// one expert's entire GEMM (W1: 16384/8 = 2048 = 64x32; W2: 4096/8 = 512 = 64x8), M innermost:
// co-resident blocks share one B-panel, and the expert's A (~4MB) becomes L2-resident.
template<bool MOE, bool GELU, bool OUTF32>
__global__ __launch_bounds__(256) void gemm_bt(
    const short* __restrict__ A, const short* __restrict__ Bt,
    const float* __restrict__ bias, void* __restrict__ Cout,
    int M, int N, int K,
    const int* __restrict__ counts, const int* __restrict__ bases,
    long bt_estride, int bias_estride)
{
    int bx = blockIdx.x, by = blockIdx.y, bz = blockIdx.z;
    int cnt = M, rowbase = 0;
    if (MOE) {
        int mB = gridDim.x, nB = gridDim.y;
        int nwg = mB * nB * gridDim.z;          // divisible by 8 for our launches
        int orig = blockIdx.x + mB * (blockIdx.y + nB * blockIdx.z);
        int cpx = nwg >> 3;
        int logical = (orig & 7) * cpx + (orig >> 3);
        int pe = mB * nB;
        bz = logical / pe;
        int rem = logical - bz * pe;
        by = rem / mB;
        bx = rem - by * mB;

        cnt = counts[bz];
        if (bx * 128 >= cnt) return;
        rowbase = bases[bz];
        Bt += (long)bz * bt_estride;
        bias += (long)bz * bias_estride;
    }
    __shared__ short As[2][128 * 32];
    __shared__ short Bs[2][128 * 32];
    int tid = threadIdx.x;
    int lane = tid & 63, wid = tid >> 6;
    int wr = (wid >> 1) * 64, wc = (wid & 1) * 64;
    int m0 = bx * 128, n0 = by * 128;

    long aoff[2]; long boff[2];
    #pragma unroll
    for (int c = 0; c < 2; c++) {
        int ch = c * 256 + tid;
        int row = ch >> 2;
        int seg = ((ch & 3) ^ swz4(row)) * 8;   // inverse-swizzled global source
        int grow = m0 + row;
        long rowidx;
        if (MOE) rowidx = rowbase + (grow < cnt ? grow : 0);
        else     rowidx = grow;
        aoff[c] = rowidx * (long)K + seg;
        boff[c] = (long)(n0 + row) * K + seg;
    }
    f32x4 acc[4][4];
    #pragma unroll
    for (int i = 0; i < 4; i++)
      #pragma unroll
      for (int j = 0; j < 4; j++) acc[i][j] = (f32x4){0.f, 0.f, 0.f, 0.f};

    int r = lane & 15, g = lane >> 4;
    const int kiters = K >> 5;

    auto stage = [&](int buf, int k0) {
        #pragma unroll
        for (int c = 0; c < 2; c++) {
            GLOAD_LDS16(A + aoff[c] + k0, &As[buf][(c * 256 + tid) * 8]);
            GLOAD_LDS16(Bt + boff[c] + k0, &Bs[buf][(c * 256 + tid) * 8]);
        }
    };

    stage(0, 0);
    __syncthreads();

    for (int kt = 0; kt < kiters; kt++) {
        int cur = kt & 1;
        if (kt + 1 < kiters) stage(cur ^ 1, (kt + 1) << 5);
        bf16x8 af[4], bfr[4];
        #pragma unroll
        for (int i = 0; i < 4; i++) {
            int ra = wr + i * 16 + r;
            af[i] = *(const bf16x8*)(&As[cur][ra * 32 + (g ^ swz4(ra)) * 8]);
        }
        #pragma unroll
        for (int j = 0; j < 4; j++) {
            int rb = wc + j * 16 + r;
            bfr[j] = *(const bf16x8*)(&Bs[cur][rb * 32 + (g ^ swz4(rb)) * 8]);
        }
        #pragma unroll
        for (int i = 0; i < 4; i++)
          #pragma unroll
          for (int j = 0; j < 4; j++)
            acc[i][j] = MFMA16x16x32(af[i], bfr[j], acc[i][j]);
        __syncthreads();
    }
    #pragma unroll
    for (int i = 0; i < 4; i++) {
      #pragma unroll
      for (int j = 0; j < 4; j++) {
        #pragma unroll
        for (int qq = 0; qq < 4; qq++) {
            int row = m0 + wr + i * 16 + g * 4 + qq;
            if (MOE && row >= cnt) continue;
            int col = n0 + wc + j * 16 + r;
            float v = acc[i][j][qq] + bias[col];
            if (GELU) v = 0.5f * v * (1.0f + erff(v * 0.70710678118f));
            long orow = MOE ? (long)(rowbase + row) : (long)row;
            if (OUTF32) ((float*)Cout)[orow * N + col] = v;
            else        ((short*)Cout)[orow * N + col] = f2bf(v);
        }
      }
    }
}

// ---------------- token gather: xg[pos] = src[gidx[pos]] (coalesced 16B lanes) ----------------
__global__ __launch_bounds__(256) void gather_kernel(const short* __restrict__ src,
    const int* __restrict__ gidx, short* __restrict__ dst)
{
    long idx = (long)blockIdx.x * 256 + threadIdx.x;
    int row = (int)(idx >> 7);
    int c = (int)(idx & 127);
    int t = gidx[row];
    *(bf16x8*)(dst + (size_t)row * D_MODEL + c * 8) =
        *(const bf16x8*)(src + (size_t)t * D_MODEL + c * 8);
}

// ---------------- split-precision flash attention: LDS-staged K/V, register P -----------------
__global__ __launch_bounds__(256) void attn_split(
    const short* __restrict__ q0p, const short* __restrict__ q1p, const short* __restrict__ q2p,
    const short* __restrict__ k0p, const short* __restrict__ k1p, const short* __restrict__ k2p,
    const short* __restrict__ v0p, const short* __restrict__ v1p, const short* __restrict__ v2p,
    short* __restrict__ ao0, short* __restrict__ ao1, short* __restrict__ ao2)
{
    __shared__ short lds[2][2][3][2048];   // [buf][K/V][plane][4KB]
    int tid = threadIdx.x;
    int wid = tid >> 6, lane = tid & 63;
    int r = lane & 15, g = lane >> 4;
    int bh = blockIdx.y;
    int b = bh >> 4, h = bh & 15, kvh = h >> 2;
    int q0_ = blockIdx.x * 64 + wid * 16;

    size_t qoff = ((size_t)(b * SEQ + q0_ + r)) * D_MODEL + h * HEAD_D + g * 8;
    bf16x8 qf[3][2];
    qf[0][0] = *(const bf16x8*)(q0p + qoff); qf[0][1] = *(const bf16x8*)(q0p + qoff + 32);
    qf[1][0] = *(const bf16x8*)(q1p + qoff); qf[1][1] = *(const bf16x8*)(q1p + qoff + 32);
    qf[2][0] = *(const bf16x8*)(q2p + qoff); qf[2][1] = *(const bf16x8*)(q2p + qoff + 32);

    size_t kbo = (size_t)(b * SEQ) * KV_D + kvh * HEAD_D;
    const short* kb[3] = {k0p + kbo, k1p + kbo, k2p + kbo};
    size_t vbo = (size_t)((b * N_KV + kvh) * HEAD_D) * SEQ;
    const short* vtp[3] = {v0p + vbo, v1p + vbo, v2p + vbo};

    int krow = tid >> 3;
    int ksrc = ((tid & 7) * 16) ^ ((krow & 7) << 4);
    int vrow = tid >> 2;
    int vsrc = ((tid & 3) * 16) ^ (((vrow >> 1) & 3) << 4);

    auto stage = [&](int buf, int kt) {
        int key0 = kt * 32;
        #pragma unroll
        for (int p = 0; p < 3; p++) {
            const short* src = kb[p] + (size_t)(key0 + krow) * KV_D + (ksrc >> 1);
            GLOAD_LDS16(src, &lds[buf][0][p][tid * 8]);
        }
        #pragma unroll
        for (int p = 0; p < 3; p++) {
            const short* src = vtp[p] + (size_t)vrow * SEQ + key0 + (vsrc >> 1);
            GLOAD_LDS16(src, &lds[buf][1][p][tid * 8]);
        }
    };

    float m_run = -1e30f, lsum = 0.f;
    f32x4 o[4];
    #pragma unroll
    for (int i = 0; i < 4; i++) o[i] = (f32x4){0.f, 0.f, 0.f, 0.f};

    stage(0, 0);
    __syncthreads();

    for (int kt = 0; kt < SEQ / 32; kt++) {
        int cur = kt & 1;
        if (kt < SEQ / 32 - 1) stage(cur ^ 1, kt + 1);

        f32x4 sT0, sT1;
        #pragma unroll
        for (int kh = 0; kh < 2; kh++) {
            f32x4 s = (f32x4){0.f, 0.f, 0.f, 0.f};
            #pragma unroll
            for (int c = 0; c < 2; c++) {
                int koff = ((kh * 16 + r) * 128 + ((c * 64 + g * 16) ^ ((r & 7) << 4))) >> 1;
                bf16x8 k0f = *(const bf16x8*)(&lds[cur][0][0][koff]);
                bf16x8 k1f = *(const bf16x8*)(&lds[cur][0][1][koff]);
                bf16x8 k2f = *(const bf16x8*)(&lds[cur][0][2][koff]);
                s = MFMA16x16x32(k0f, qf[0][c], s);
                s = MFMA16x16x32(k1f, qf[0][c], s);
                s = MFMA16x16x32(k0f, qf[1][c], s);
                s = MFMA16x16x32(k2f, qf[0][c], s);
                s = MFMA16x16x32(k1f, qf[1][c], s);
                s = MFMA16x16x32(k0f, qf[2][c], s);
            }
            if (kh == 0) sT0 = s; else sT1 = s;
        }

        float a0[4], a1[4];
        float vmx = -1e30f;
        #pragma unroll
        for (int rr = 0; rr < 4; rr++) {
            a0[rr] = sT0[rr] * 0.125f;
            a1[rr] = sT1[rr] * 0.125f;
            vmx = fmaxf(vmx, fmaxf(a0[rr], a1[rr]));
        }
        vmx = fmaxf(vmx, __shfl_xor(vmx, 16));
        vmx = fmaxf(vmx, __shfl_xor(vmx, 32));
        float mn = fmaxf(m_run, vmx);
        float alpha = __expf(m_run - mn);
        m_run = mn;
        float p0[4], p1[4], ps = 0.f;
        #pragma unroll
        for (int rr = 0; rr < 4; rr++) {
            p0[rr] = __expf(a0[rr] - mn);
            p1[rr] = __expf(a1[rr] - mn);
            ps += p0[rr] + p1[rr];
        }
        ps += __shfl_xor(ps, 16);
        ps += __shfl_xor(ps, 32);
        lsum = lsum * alpha + ps;
        bf16x8 pw0, pw1, pw2;
        #pragma unroll
        for (int rr = 0; rr < 4; rr++) {
            short h0_, m0_, l0_, h1_, m1_, l1_;
            split3(p0[rr], h0_, m0_, l0_);
            split3(p1[rr], h1_, m1_, l1_);
            pw0[rr] = h0_; pw0[4 + rr] = h1_;
            pw1[rr] = m0_; pw1[4 + rr] = m1_;
            pw2[rr] = l0_; pw2[4 + rr] = l1_;
        }
        float af[4];
        #pragma unroll
        for (int rr = 0; rr < 4; rr++) af[rr] = __shfl(alpha, g * 4 + rr);
        #pragma unroll
        for (int fc = 0; fc < 4; fc++)
          #pragma unroll
          for (int rr = 0; rr < 4; rr++) o[fc][rr] *= af[rr];

        #pragma unroll
        for (int fc = 0; fc < 4; fc++) {
            int voff = ((fc * 16 + r) * 64 + ((g * 16) ^ (((r >> 1) & 3) << 4))) >> 1;
            bf16x8 bv0 = *(const bf16x8*)(&lds[cur][1][0][voff]);
            bf16x8 bv1 = *(const bf16x8*)(&lds[cur][1][1][voff]);
            bf16x8 bv2 = *(const bf16x8*)(&lds[cur][1][2][voff]);
            f32x4 a = o[fc];
            a = MFMA16x16x32(pw0, bv0, a);
            a = MFMA16x16x32(pw0, bv1, a);
            a = MFMA16x16x32(pw1, bv0, a);
            a = MFMA16x16x32(pw0, bv2, a);
            a = MFMA16x16x32(pw1, bv1, a);
            a = MFMA16x16x32(pw2, bv0, a);
            o[fc] = a;
        }

        __syncthreads();
    }

    float linv[4];
    #pragma unroll
    for (int rr = 0; rr < 4; rr++) linv[rr] = 1.0f / __shfl(lsum, g * 4 + rr);
    #pragma unroll
    for (int fc = 0; fc < 4; fc++) {
        #pragma unroll
        for (int rr = 0; rr < 4; rr++) {
            float v = o[fc][rr] * linv[rr];
            int qrow = q0_ + g * 4 + rr;
            int col = h * HEAD_D + fc * 16 + r;
            size_t oi = ((size_t)(b * SEQ + qrow)) * D_MODEL + col;
            short a_, b_, c_;
            split3(v, a_, b_, c_);
            ao0[oi] = a_; ao1[oi] = b_; ao2[oi] = c_;
        }
    }
}

// ---------------- router (f32 exact, no atomics) ----------------------------------------------
__global__ __launch_bounds__(256) void router_kernel(
    const float* __restrict__ h2f, const float* __restrict__ Wr, const float* __restrict__ br,
    int* __restrict__ topi, float* __restrict__ topw)
{
    int wid = threadIdx.x >> 6, lane = threadIdx.x & 63;
    int t = blockIdx.x * 4 + wid;
    const float4* hr = (const float4*)(h2f + (size_t)t * D_MODEL + lane * 16);
    float acc[8] = {0.f,0.f,0.f,0.f,0.f,0.f,0.f,0.f};
    #pragma unroll
    for (int ii = 0; ii < 4; ii++) {
        float4 hv4 = hr[ii];
        float hv[4] = {hv4.x, hv4.y, hv4.z, hv4.w};
        #pragma unroll
        for (int c = 0; c < 4; c++) {
            int idx = lane * 16 + ii * 4 + c;
            const float4* w4 = (const float4*)(Wr + (size_t)idx * 8);
            float4 w0 = w4[0], w1 = w4[1];
            acc[0] += hv[c] * w0.x; acc[1] += hv[c] * w0.y;
            acc[2] += hv[c] * w0.z; acc[3] += hv[c] * w0.w;
            acc[4] += hv[c] * w1.x; acc[5] += hv[c] * w1.y;
            acc[6] += hv[c] * w1.z; acc[7] += hv[c] * w1.w;
        }
    }
    #pragma unroll
    for (int e = 0; e < 8; e++) {
        float v = acc[e];
        #pragma unroll
        for (int o = 32; o > 0; o >>= 1) v += __shfl_xor(v, o);
        acc[e] = v + br[e];
    }
    if (lane == 0) {
        int i0 = 0; float l0 = acc[0];
        #pragma unroll
        for (int e = 1; e < 8; e++) if (acc[e] > l0) { l0 = acc[e]; i0 = e; }
        int i1 = -1; float l1 = -1e30f;
        #pragma unroll
        for (int e = 0; e < 8; e++) if (e != i0 && acc[e] > l1) { l1 = acc[e]; i1 = e; }
        float e1 = expf(l1 - l0);
        float w0 = 1.0f / (1.0f + e1);
        topi[t * 2] = i0; topi[t * 2 + 1] = i1;
        topw[t * 2] = w0; topw[t * 2 + 1] = e1 * w0;
    }
}

// ---------------- histogram + prefix (1 block) ------------------------------------------------
__global__ __launch_bounds__(1024) void hist_kernel(const int* __restrict__ topi,
    int* __restrict__ counts, int* __restrict__ bases, int* __restrict__ cursor)
{
    __shared__ int hc[8];
    int tid = threadIdx.x;
    if (tid < 8) hc[tid] = 0;
    __syncthreads();
    int c[8] = {0,0,0,0,0,0,0,0};
    for (int i = tid; i < 2 * T_TOK; i += 1024) {
        int e = topi[i];
        #pragma unroll
        for (int q = 0; q < 8; q++) c[q] += (e == q) ? 1 : 0;
    }
    #pragma unroll
    for (int e = 0; e < 8; e++) {
        int v = c[e];
        #pragma unroll
        for (int o = 32; o > 0; o >>= 1) v += __shfl_xor(v, o);
        if ((tid & 63) == 0) atomicAdd(&hc[e], v);
    }
    __syncthreads();
    if (tid == 0) {
        int s = 0;
        #pragma unroll
        for (int e = 0; e < 8; e++) { bases[e] = s; counts[e] = hc[e]; s += hc[e]; }
    }
    if (tid >= 64 && tid < 72) cursor[tid - 64] = 0;
}

// ---------------- assign with wave-aggregated atomics -----------------------------------------
__global__ __launch_bounds__(256) void assign_kernel(const int* __restrict__ topi,
    const int* __restrict__ bases, int* __restrict__ cursor,
    int* __restrict__ gidx, int* __restrict__ pos_of)
{
    int t = blockIdx.x * 256 + threadIdx.x;
    int lane = threadIdx.x & 63;
    #pragma unroll
    for (int kk = 0; kk < 2; kk++) {
        int e = topi[t * 2 + kk];
        #pragma unroll
        for (int e8 = 0; e8 < 8; e8++) {
            bool mine = (e == e8);
            unsigned long long m = __ballot(mine);
            if (m == 0ull) continue;
            int lead = __ffsll((long long)m) - 1;
            int base = 0;
            if (lane == lead) base = atomicAdd(&cursor[e8], __popcll(m));
            base = __shfl(base, lead);
            if (mine) {
                int pos = bases[e8] + base + (int)__popcll(m & ((1ull << lane) - 1ull));
                gidx[pos] = t;
                pos_of[t * 2 + kk] = pos;
            }
        }
    }
}

__global__ void biascat_kernel(const float* __restrict__ bq, const float* __restrict__ bk,
                               const float* __restrict__ bv, float* __restrict__ out)
{
    int i = blockIdx.x * 256 + threadIdx.x;
    if (i < 1024) out[i] = bq[i];
    else if (i < 1280) out[i] = bk[i - 1024];
    else if (i < 1536) out[i] = bv[i - 1280];
}

__global__ __launch_bounds__(256) void combine_kernel(const float* __restrict__ x2,
    const float* __restrict__ y, const int* __restrict__ pos_of,
    const float* __restrict__ topw, float* __restrict__ out)
{
    long idx = (long)blockIdx.x * 256 + threadIdx.x;
    int t = (int)(idx >> 8);
    int c = (int)(idx & 255);
    int p0 = pos_of[t * 2], p1 = pos_of[t * 2 + 1];
    float w0 = topw[t * 2], w1 = topw[t * 2 + 1];
    float4 a = ((const float4*)(x2 + (size_t)t * D_MODEL))[c];
    float4 u = ((const float4*)(y + (size_t)p0 * D_MODEL))[c];
    float4 v = ((const float4*)(y + (size_t)p1 * D_MODEL))[c];
    float4 o;
    o.x = a.x + w0 * u.x + w1 * v.x;
    o.y = a.y + w0 * u.y + w1 * v.y;
    o.z = a.z + w0 * u.z + w1 * v.z;
    o.w = a.w + w0 * u.w + w1 * v.w;
    ((float4*)(out + (size_t)t * D_MODEL))[c] = o;
}

extern "C" void kernel_launch(void* const* d_in, const int* in_sizes, int n_in,
                              void* d_out, int out_size, void* d_ws, size_t ws_size,
                              hipStream_t stream)
{
    (void)in_sizes; (void)n_in; (void)out_size; (void)ws_size;
    const float* x   = (const float*)d_in[0];
    const float* Wq  = (const float*)d_in[1];
    const float* bq  = (const float*)d_in[2];
    const float* Wk  = (const float*)d_in[3];
    const float* bk  = (const float*)d_in[4];
    const float* Wv  = (const float*)d_in[5];
    const float* bv  = (const float*)d_in[6];
    const float* Wo  = (const float*)d_in[7];
    const float* bo  = (const float*)d_in[8];
    const float* g1  = (const float*)d_in[9];
    const float* b1n = (const float*)d_in[10];
    const float* g2  = (const float*)d_in[11];
    const float* b2n = (const float*)d_in[12];
    const float* Wr  = (const float*)d_in[13];
    const float* br  = (const float*)d_in[14];
    const float* W1  = (const float*)d_in[15];
    const float* b1e = (const float*)d_in[16];
    const float* W2  = (const float*)d_in[17];
    const float* b2e = (const float*)d_in[18];
    float* out = (float*)d_out;

    size_t off = 0;
    auto alloc = [&](size_t n) {
        size_t cur = off;
        off = (cur + n + 255) & ~(size_t)255;
        return (void*)((char*)d_ws + cur);
    };
    const size_t PD = (size_t)T_TOK * D_MODEL;
    const size_t PK = (size_t)T_TOK * KV_D;
    const size_t WQKV = (size_t)1536 * 1024;
    const size_t WQP  = (size_t)D_MODEL * D_MODEL;
    short* blkA   = (short*)alloc(3 * PD * 2);       // h planes -> ao planes -> xg (aliased)
    short* blkB   = (short*)alloc(3 * PD * 2);       // q planes -> h2hi + h2f
    short* kpl    = (short*)alloc(3 * PK * 2);
    short* vbpl   = (short*)alloc(3 * PK * 2);
    short* vtpl   = (short*)alloc(3 * PK * 2);
    float* x2     = (float*)alloc(PD * 4);
    short* WqkvT3 = (short*)alloc(3 * WQKV * 2);
    short* WoT3   = (short*)alloc(3 * WQP * 2);
    float* bqkv   = (float*)alloc(1536 * 4);
    short* W1T    = (short*)alloc((size_t)N_EXP * H_FF * D_MODEL * 2);
    short* W2T    = (short*)alloc((size_t)N_EXP * D_MODEL * H_FF * 2);
    short* mid    = (short*)alloc((size_t)(2 * T_TOK) * H_FF * 2);
    float* yb     = (float*)alloc((size_t)(2 * T_TOK) * D_MODEL * 4);
    int* counts = (int*)alloc(256);
    int* bases  = (int*)alloc(256);
    int* cursor = (int*)alloc(256);
    int* topi   = (int*)alloc((size_t)T_TOK * 2 * 4);
    float* topw = (float*)alloc((size_t)T_TOK * 2 * 4);
    int* posof  = (int*)alloc((size_t)T_TOK * 2 * 4);
    int* gidx   = (int*)alloc((size_t)2 * T_TOK * 4);

    short* h0 = blkA, *h1 = blkA + PD, *h2p = blkA + 2 * PD;
    short* ao0 = blkA, *ao1 = blkA + PD, *ao2 = blkA + 2 * PD;
    short* xg = blkA;   // alias: blkA (h/ao planes) is dead after the O-projection;
                        // gather (32 MiB) runs strictly later.
    short* q0 = blkB, *q1 = blkB + PD, *q2 = blkB + 2 * PD;
    short* h2hi = blkB;
    float* h2f = (float*)(blkB + PD);
    short* k0 = kpl, *k1 = kpl + PK, *k2 = kpl + 2 * PK;
    short* vb0 = vbpl, *vb1 = vbpl + PK, *vb2 = vbpl + 2 * PK;
    short* vt0 = vtpl, *vt1 = vtpl + PK, *vt2 = vtpl + 2 * PK;

    dim3 tb(32, 8);
    transpose_f2b3<<<dim3(32, 32), tb, 0, stream>>>(Wq, WqkvT3,                   (long)WQKV, 1024, 1024);
    transpose_f2b3<<<dim3(8, 32),  tb, 0, stream>>>(Wk, WqkvT3 + (size_t)1024 * 1024, (long)WQKV, 1024, 256);
    transpose_f2b3<<<dim3(8, 32),  tb, 0, stream>>>(Wv, WqkvT3 + (size_t)1280 * 1024, (long)WQKV, 1024, 256);
    transpose_f2b3<<<dim3(32, 32), tb, 0, stream>>>(Wo, WoT3, (long)WQP, 1024, 1024);
    transpose_f2b<<<dim3(128, 32, 8), tb, 0, stream>>>(W1, W1T, 1024, 4096,
        (long)1024 * 4096, (long)4096 * 1024);
    transpose_f2b<<<dim3(32, 128, 8), tb, 0, stream>>>(W2, W2T, 4096, 1024,
        (long)4096 * 1024, (long)1024 * 4096);
    biascat_kernel<<<6, 256, 0, stream>>>(bq, bk, bv, bqkv);

    ln_kernel<0><<<T_TOK, 256, 0, stream>>>(x, g1, b1n, h0, h1, h2p, nullptr);

    // fused QKV projection
    gemm_split<2, false><<<dim3(64, 12), 256, 0, stream>>>(
        h0, h1, h2p, WqkvT3, WqkvT3 + WQKV, WqkvT3 + 2 * WQKV, bqkv,
        q0, q1, q2, k0, k1, k2, vb0, vb1, vb2,
        nullptr, nullptr, T_TOK, 1536, 1024);

    vperm_kernel<<<dim3(32, 8, 24), tb, 0, stream>>>(vbpl, vtpl, (long)PK, (long)PK);

    attn_split<<<dim3(16, 128), 256, 0, stream>>>(q0, q1, q2, k0, k1, k2,
        vt0, vt1, vt2, ao0, ao1, ao2);

    gemm_split<0, true><<<dim3(64, 8), 256, 0, stream>>>(
        ao0, ao1, ao2, WoT3, WoT3 + WQP, WoT3 + 2 * WQP, bo,
        nullptr, nullptr, nullptr, nullptr, nullptr, nullptr, nullptr, nullptr, nullptr,
        x2, x, T_TOK, 1024, 1024);

    ln_kernel<1><<<T_TOK, 256, 0, stream>>>(x2, g2, b2n, h2hi, nullptr, nullptr, h2f);

    router_kernel<<<2048, 256, 0, stream>>>(h2f, Wr, br, topi, topw);
    hist_kernel<<<1, 1024, 0, stream>>>(topi, counts, bases, cursor);
    assign_kernel<<<32, 256, 0, stream>>>(topi, bases, cursor, gidx, posof);
    gather_kernel<<<8192, 256, 0, stream>>>(h2hi, gidx, xg);

    gemm_bt<true, true, false><<<dim3(64, 32, 8), 256, 0, stream>>>(
        xg, W1T, b1e, mid, 0, 4096, 1024, counts, bases,
        (long)H_FF * D_MODEL, H_FF);
    gemm_bt<true, false, true><<<dim3(64, 8, 8), 256, 0, stream>>>(
        mid, W2T, b2e, yb, 0, 1024, 4096, counts, bases,
        (long)D_MODEL * H_FF, D_MODEL);

    combine_kernel<<<8192, 256, 0, stream>>>(x2, yb, posof, topw, out);
}